// Round 4
// baseline (3982.711 us; speedup 1.0000x reference)
//
#include <hip/hip_runtime.h>
#include <hip/hip_bf16.h>

namespace {

constexpr int N = 50000;
constexpr int E = 300000;
constexpr int G = 256;
constexpr int H = 256;
constexpr float EPS = 1e-5f;

__device__ __forceinline__ float sp(float z){
  // jax.nn.softplus = max(z,0) + log1p(exp(-|z|))
  return fmaxf(z, 0.f) + log1pf(expf(-fabsf(z)));
}

// h[i,f] = node_emb_w[node_type[i], f]
__global__ void k_embed(const int* __restrict__ nt, const float* __restrict__ emb,
                        float* __restrict__ x){
  int idx = blockIdx.x * 256 + threadIdx.x;
  if (idx >= N * 64) return;
  int i = idx >> 6, fq = (idx & 63) << 2;
  *(float4*)(x + i * H + fq) = *(const float4*)(emb + nt[i] * H + fq);
}

// agg[dst] += softplus(x[src] + edge_emb[edge_type]); agg pre-initialized with x (residual)
__global__ void k_scatter(const float* __restrict__ x, float* __restrict__ agg,
                          const int* __restrict__ src, const int* __restrict__ dst,
                          const int* __restrict__ et, const float* __restrict__ eemb){
  int idx = blockIdx.x * 256 + threadIdx.x;
  if (idx >= E * 64) return;
  int e = idx >> 6, fq = (idx & 63) << 2;
  int s = src[e], d = dst[e], t = et[e];
  float4 xv = *(const float4*)(x + s * H + fq);
  float4 ev = *(const float4*)(eemb + t * H + fq);
  float* ap = agg + d * H + fq;
  atomicAdd(ap + 0, sp(xv.x + ev.x));
  atomicAdd(ap + 1, sp(xv.y + ev.y));
  atomicAdd(ap + 2, sp(xv.z + ev.z));
  atomicAdd(ap + 3, sp(xv.w + ev.w));
}

// per-feature sum / sumsq over N rows; blockDim.x == F
__global__ void k_stats(const float* __restrict__ y, float* __restrict__ sums,
                        float* __restrict__ sumsq, int F){
  int f = threadIdx.x;
  float s = 0.f, s2 = 0.f;
  for (int i = blockIdx.x; i < N; i += gridDim.x){
    float v = y[i * F + f];
    s += v; s2 += v * v;
  }
  atomicAdd(&sums[f], s);
  atomicAdd(&sumsq[f], s2);
}

__global__ void k_bnparams(const float* __restrict__ sums, const float* __restrict__ sumsq,
                           const float* __restrict__ gamma, const float* __restrict__ beta,
                           float* __restrict__ a, float* __restrict__ c){
  int f = threadIdx.x;
  float mean = sums[f] * (1.f / N);
  float var = sumsq[f] * (1.f / N) - mean * mean;   // biased var, matches x.var()
  float rstd = rsqrtf(var + EPS);
  float av = gamma[f] * rstd;
  a[f] = av;
  c[f] = beta[f] - mean * av;
}

template<int ACT>
__global__ void k_norm(const float* __restrict__ in, float* __restrict__ out,
                       const float* __restrict__ a, const float* __restrict__ c,
                       int n4, int fmask){
  int idx = blockIdx.x * 256 + threadIdx.x;
  if (idx >= n4) return;
  int base = idx << 2;
  int f = base & fmask;
  float4 v = *(const float4*)(in + base);
  float4 av = *(const float4*)(a + f);
  float4 cv = *(const float4*)(c + f);
  v.x = av.x * v.x + cv.x;
  v.y = av.y * v.y + cv.y;
  v.z = av.z * v.z + cv.z;
  v.w = av.w * v.w + cv.w;
  if (ACT){ v.x = sp(v.x); v.y = sp(v.y); v.z = sp(v.z); v.w = sp(v.w); }
  *(float4*)(out + base) = v;
}

// hg[batch[i]] += x[i]
__global__ void k_pool(const float* __restrict__ x, const int* __restrict__ batch,
                       float* __restrict__ hg){
  int idx = blockIdx.x * 256 + threadIdx.x;
  if (idx >= N * 64) return;
  int i = idx >> 6, fq = (idx & 63) << 2;
  int g = batch[i];
  float4 v = *(const float4*)(x + i * H + fq);
  float* p = hg + g * H + fq;
  atomicAdd(p + 0, v.x);
  atomicAdd(p + 1, v.y);
  atomicAdd(p + 2, v.z);
  atomicAdd(p + 3, v.w);
}

// Tiled GEMM: [N,K] fp32 x [K,NC] fp32 + bias
// AMODE 0: plain A (lda=K).  AMODE 1: concat loader (K=512, first 256 from A=x, rest hg[batch[r]]).
// SMODE 0: fp32 out [N,NC].  SMODE 1: fp32 split store to d_out (NC=128, halves at 64).
template<int AMODE, int SMODE>
__global__ void k_gemm(const float* __restrict__ A, const float* __restrict__ hg,
                       const int* __restrict__ batch, const float* __restrict__ W,
                       const float* __restrict__ bias, float* __restrict__ out,
                       float* __restrict__ outsplit, int K, int NC){
  __shared__ float As[64][17];
  __shared__ float Bs[16][68];
  int tid = threadIdx.x;
  int tx = tid & 15, ty = tid >> 4;
  int rowBase = blockIdx.x * 64, colBase = blockIdx.y * 64;
  int am = tid >> 2, ak = (tid & 3) << 2;   // A tile: row am, k4 chunk ak
  int bk = tid >> 4, bc = (tid & 15) << 2;  // B tile: k row bk, col chunk bc
  float acc[4][4] = {};
  for (int k0 = 0; k0 < K; k0 += 16){
    int r = rowBase + am;
    float4 av = make_float4(0.f, 0.f, 0.f, 0.f);
    if (r < N){
      int kg = k0 + ak;
      if (AMODE == 0){
        av = *(const float4*)(A + r * K + kg);
      } else {
        if (kg < H) av = *(const float4*)(A + r * H + kg);
        else        av = *(const float4*)(hg + batch[r] * H + (kg - H));
      }
    }
    As[am][ak + 0] = av.x; As[am][ak + 1] = av.y;
    As[am][ak + 2] = av.z; As[am][ak + 3] = av.w;
    float4 wv = *(const float4*)(W + (k0 + bk) * NC + colBase + bc);
    Bs[bk][bc + 0] = wv.x; Bs[bk][bc + 1] = wv.y;
    Bs[bk][bc + 2] = wv.z; Bs[bk][bc + 3] = wv.w;
    __syncthreads();
    #pragma unroll
    for (int kk = 0; kk < 16; ++kk){
      float a0 = As[ty * 4 + 0][kk];
      float a1 = As[ty * 4 + 1][kk];
      float a2 = As[ty * 4 + 2][kk];
      float a3 = As[ty * 4 + 3][kk];
      float b0 = Bs[kk][tx * 4 + 0];
      float b1 = Bs[kk][tx * 4 + 1];
      float b2 = Bs[kk][tx * 4 + 2];
      float b3 = Bs[kk][tx * 4 + 3];
      acc[0][0] += a0 * b0; acc[0][1] += a0 * b1; acc[0][2] += a0 * b2; acc[0][3] += a0 * b3;
      acc[1][0] += a1 * b0; acc[1][1] += a1 * b1; acc[1][2] += a1 * b2; acc[1][3] += a1 * b3;
      acc[2][0] += a2 * b0; acc[2][1] += a2 * b1; acc[2][2] += a2 * b2; acc[2][3] += a2 * b3;
      acc[3][0] += a3 * b0; acc[3][1] += a3 * b1; acc[3][2] += a3 * b2; acc[3][3] += a3 * b3;
    }
    __syncthreads();
  }
  #pragma unroll
  for (int i = 0; i < 4; ++i){
    int r = rowBase + ty * 4 + i;
    if (r >= N) continue;
    #pragma unroll
    for (int j = 0; j < 4; ++j){
      int cidx = colBase + tx * 4 + j;
      float v = acc[i][j] + bias[cidx];
      if (SMODE == 0){
        out[r * NC + cidx] = v;
      } else {
        if (cidx < 64) outsplit[r * 64 + cidx] = v;                     // mu
        else           outsplit[(size_t)N * 64 + r * 64 + (cidx - 64)] = v;  // logvar
      }
    }
  }
}

} // namespace

extern "C" void kernel_launch(void* const* d_in, const int* in_sizes, int n_in,
                              void* d_out, int out_size, void* d_ws, size_t ws_size,
                              hipStream_t stream){
  const int* node_type = (const int*)d_in[0];
  const int* edge_type = (const int*)d_in[1];
  const int* src       = (const int*)d_in[2];
  const int* dst       = src + E;
  const int* batch     = (const int*)d_in[3];
  const float* nemb = (const float*)d_in[4];
  const float* eemb = (const float*)d_in[5];
  const float* gs[3] = {(const float*)d_in[6], (const float*)d_in[8], (const float*)d_in[10]};
  const float* bs[3] = {(const float*)d_in[7], (const float*)d_in[9], (const float*)d_in[11]};
  const float* go1 = (const float*)d_in[12]; const float* bo1 = (const float*)d_in[13];
  const float* go2 = (const float*)d_in[14]; const float* bo2 = (const float*)d_in[15];
  const float* W1 = (const float*)d_in[16]; const float* B1 = (const float*)d_in[17];
  const float* W2 = (const float*)d_in[18]; const float* B2 = (const float*)d_in[19];
  const float* W3 = (const float*)d_in[20]; const float* B3 = (const float*)d_in[21];
  float* outf = (float*)d_out;

  float* ws   = (float*)d_ws;
  float* x    = ws;                           // [N,H] current features
  float* agg  = x   + (size_t)N * H;          // [N,H] aggregation / Y1 / Z1
  float* hg   = agg + (size_t)N * H;          // [G,H]
  float* stats = hg + (size_t)G * H;          // sums|sumsq|a|c (256 each)
  float* sums = stats, *sumsq = stats + 256, *aArr = stats + 512, *cArr = stats + 768;

  k_embed<<<(N * 64 + 255) / 256, 256, 0, stream>>>(node_type, nemb, x);

  for (int l = 0; l < 3; ++l){
    hipMemcpyAsync(agg, x, (size_t)N * H * sizeof(float), hipMemcpyDeviceToDevice, stream);
    k_scatter<<<(E * 64 + 255) / 256, 256, 0, stream>>>(x, agg, src, dst, edge_type, eemb);
    hipMemsetAsync(sums, 0, 512 * sizeof(float), stream);
    k_stats<<<512, H, 0, stream>>>(agg, sums, sumsq, H);
    k_bnparams<<<1, H, 0, stream>>>(sums, sumsq, gs[l], bs[l], aArr, cArr);
    if (l < 2)
      k_norm<1><<<(N * H / 4 + 255) / 256, 256, 0, stream>>>(agg, x, aArr, cArr, N * H / 4, H - 1);
    else
      k_norm<0><<<(N * H / 4 + 255) / 256, 256, 0, stream>>>(agg, x, aArr, cArr, N * H / 4, H - 1);
  }

  hipMemsetAsync(hg, 0, (size_t)G * H * sizeof(float), stream);
  k_pool<<<(N * 64 + 255) / 256, 256, 0, stream>>>(x, batch, hg);

  // GEMM1: [h | hg[batch]] (N,512) @ W1 (512,256) + B1 -> agg
  {
    dim3 grid((N + 63) / 64, 256 / 64);
    k_gemm<1, 0><<<grid, 256, 0, stream>>>(x, hg, batch, W1, B1, agg, nullptr, 512, 256);
  }
  hipMemsetAsync(sums, 0, 512 * sizeof(float), stream);
  k_stats<<<512, 256, 0, stream>>>(agg, sums, sumsq, 256);
  k_bnparams<<<1, 256, 0, stream>>>(sums, sumsq, go1, bo1, aArr, cArr);
  k_norm<1><<<(N * 256 / 4 + 255) / 256, 256, 0, stream>>>(agg, agg, aArr, cArr, N * 256 / 4, 255);

  // GEMM2: Z1 (N,256) @ W2 (256,128) + B2 -> x
  {
    dim3 grid((N + 63) / 64, 128 / 64);
    k_gemm<0, 0><<<grid, 256, 0, stream>>>(agg, nullptr, nullptr, W2, B2, x, nullptr, 256, 128);
  }
  hipMemsetAsync(sums, 0, 512 * sizeof(float), stream);
  k_stats<<<512, 128, 0, stream>>>(x, sums, sumsq, 128);
  k_bnparams<<<1, 128, 0, stream>>>(sums, sumsq, go2, bo2, aArr, cArr);
  k_norm<1><<<(N * 128 / 4 + 255) / 256, 256, 0, stream>>>(x, x, aArr, cArr, N * 128 / 4, 127);

  // GEMM3: Z2 (N,128) @ W3 (128,128) + B3 -> fp32 split store to d_out
  {
    dim3 grid((N + 63) / 64, 128 / 64);
    k_gemm<0, 1><<<grid, 256, 0, stream>>>(x, nullptr, nullptr, W3, B3, nullptr, outf, 128, 128);
  }
}

// Round 5
// 1610.443 us; speedup vs baseline: 2.4731x; 2.4731x over previous
//
#include <hip/hip_runtime.h>
#include <hip/hip_bf16.h>

namespace {

constexpr int N = 50000;
constexpr int E = 300000;
constexpr int G = 256;
constexpr int H = 256;
constexpr float EPS = 1e-5f;
constexpr int SCAN_T = 1024;

__device__ __forceinline__ float sp(float z){
  // jax.nn.softplus = max(z,0) + log1p(exp(-|z|))
  return fmaxf(z, 0.f) + log1pf(expf(-fabsf(z)));
}

// h[i,f] = node_emb_w[node_type[i], f]
__global__ void k_embed(const int* __restrict__ nt, const float* __restrict__ emb,
                        float* __restrict__ x){
  int idx = blockIdx.x * 256 + threadIdx.x;
  if (idx >= N * 64) return;
  int i = idx >> 6, fq = (idx & 63) << 2;
  *(float4*)(x + i * H + fq) = *(const float4*)(emb + nt[i] * H + fq);
}

// ---- CSR build (by dst) ----
__global__ void k_hist(const int* __restrict__ dst, int* __restrict__ cnt){
  int e = blockIdx.x * 256 + threadIdx.x;
  if (e < E) atomicAdd(&cnt[dst[e]], 1);
}

// single-block exclusive scan of cnt[N] -> off[N] (+ off[N]=E), cur = off copy
__global__ void k_scan(const int* __restrict__ cnt, int* __restrict__ off,
                       int* __restrict__ cur){
  __shared__ int part[SCAN_T];
  int t = threadIdx.x;
  const int C = (N + SCAN_T - 1) / SCAN_T;
  int base = t * C;
  int s = 0;
  for (int k = 0; k < C; ++k){
    int i = base + k;
    if (i < N) s += cnt[i];
  }
  part[t] = s;
  __syncthreads();
  for (int d = 1; d < SCAN_T; d <<= 1){
    int v = (t >= d) ? part[t - d] : 0;
    __syncthreads();
    part[t] += v;
    __syncthreads();
  }
  int run = (t == 0) ? 0 : part[t - 1];
  for (int k = 0; k < C; ++k){
    int i = base + k;
    if (i < N){
      int c = cnt[i];
      off[i] = run; cur[i] = run;
      run += c;
    }
  }
  if (t == SCAN_T - 1) off[N] = run;
}

// edges_s[p] = (src, edge_type) sorted by dst
__global__ void k_fill(const int* __restrict__ src, const int* __restrict__ dst,
                       const int* __restrict__ et, int* __restrict__ cur,
                       int2* __restrict__ edges_s){
  int e = blockIdx.x * 256 + threadIdx.x;
  if (e >= E) return;
  int d = dst[e];
  int p = atomicAdd(&cur[d], 1);
  edges_s[p] = make_int2(src[e], et[e]);
}

// agg[i] = x[i] + sum_{e: dst=i} softplus(x[src_e] + eemb[et_e]); one wave per node
__global__ void k_gather(const float* __restrict__ x, float* __restrict__ agg,
                         const int2* __restrict__ edges_s, const int* __restrict__ off,
                         const float* __restrict__ eemb){
  int gt = blockIdx.x * 256 + threadIdx.x;
  int i = gt >> 6;
  if (i >= N) return;
  int fq = (gt & 63) << 2;
  float4 acc = *(const float4*)(x + (size_t)i * H + fq);
  int lo = off[i], hi = off[i + 1];
  for (int j = lo; j < hi; ++j){
    int2 se = edges_s[j];
    float4 xv = *(const float4*)(x + (size_t)se.x * H + fq);
    float4 ev = *(const float4*)(eemb + (size_t)se.y * H + fq);
    acc.x += sp(xv.x + ev.x);
    acc.y += sp(xv.y + ev.y);
    acc.z += sp(xv.z + ev.z);
    acc.w += sp(xv.w + ev.w);
  }
  *(float4*)(agg + (size_t)i * H + fq) = acc;
}

// per-feature sum / sumsq over N rows; blockDim.x == F
__global__ void k_stats(const float* __restrict__ y, float* __restrict__ sums,
                        float* __restrict__ sumsq, int F){
  int f = threadIdx.x;
  float s = 0.f, s2 = 0.f;
  for (int i = blockIdx.x; i < N; i += gridDim.x){
    float v = y[i * F + f];
    s += v; s2 += v * v;
  }
  atomicAdd(&sums[f], s);
  atomicAdd(&sumsq[f], s2);
}

__global__ void k_bnparams(const float* __restrict__ sums, const float* __restrict__ sumsq,
                           const float* __restrict__ gamma, const float* __restrict__ beta,
                           float* __restrict__ a, float* __restrict__ c){
  int f = threadIdx.x;
  float mean = sums[f] * (1.f / N);
  float var = sumsq[f] * (1.f / N) - mean * mean;   // biased var, matches x.var()
  float rstd = rsqrtf(var + EPS);
  float av = gamma[f] * rstd;
  a[f] = av;
  c[f] = beta[f] - mean * av;
}

template<int ACT>
__global__ void k_norm(const float* __restrict__ in, float* __restrict__ out,
                       const float* __restrict__ a, const float* __restrict__ c,
                       int n4, int fmask){
  int idx = blockIdx.x * 256 + threadIdx.x;
  if (idx >= n4) return;
  int base = idx << 2;
  int f = base & fmask;
  float4 v = *(const float4*)(in + base);
  float4 av = *(const float4*)(a + f);
  float4 cv = *(const float4*)(c + f);
  v.x = av.x * v.x + cv.x;
  v.y = av.y * v.y + cv.y;
  v.z = av.z * v.z + cv.z;
  v.w = av.w * v.w + cv.w;
  if (ACT){ v.x = sp(v.x); v.y = sp(v.y); v.z = sp(v.z); v.w = sp(v.w); }
  *(float4*)(out + base) = v;
}

// segmented pool: batch sorted; one block per group, thread = feature
__global__ void k_pool_seg(const float* __restrict__ x, const int* __restrict__ batch,
                           float* __restrict__ hg){
  int g = blockIdx.x;
  int f = threadIdx.x;
  int lo = 0, hi = N;
  while (lo < hi){ int m = (lo + hi) >> 1; if (batch[m] < g) lo = m + 1; else hi = m; }
  int start = lo;
  lo = 0; hi = N;
  while (lo < hi){ int m = (lo + hi) >> 1; if (batch[m] < g + 1) lo = m + 1; else hi = m; }
  int end = lo;
  float s = 0.f;
  for (int i = start; i < end; ++i) s += x[(size_t)i * H + f];
  hg[g * H + f] = s;
}

// Tiled GEMM: [N,K] fp32 x [K,NC] fp32 + bias
// AMODE 0: plain A (lda=K).  AMODE 1: concat loader (K=512, first 256 from A=x, rest hg[batch[r]]).
// SMODE 0: fp32 out [N,NC].  SMODE 1: fp32 split store to d_out (NC=128, halves at 64).
template<int AMODE, int SMODE>
__global__ void k_gemm(const float* __restrict__ A, const float* __restrict__ hg,
                       const int* __restrict__ batch, const float* __restrict__ W,
                       const float* __restrict__ bias, float* __restrict__ out,
                       float* __restrict__ outsplit, int K, int NC){
  __shared__ float As[64][17];
  __shared__ float Bs[16][68];
  int tid = threadIdx.x;
  int tx = tid & 15, ty = tid >> 4;
  int rowBase = blockIdx.x * 64, colBase = blockIdx.y * 64;
  int am = tid >> 2, ak = (tid & 3) << 2;
  int bk = tid >> 4, bc = (tid & 15) << 2;
  float acc[4][4] = {};
  for (int k0 = 0; k0 < K; k0 += 16){
    int r = rowBase + am;
    float4 av = make_float4(0.f, 0.f, 0.f, 0.f);
    if (r < N){
      int kg = k0 + ak;
      if (AMODE == 0){
        av = *(const float4*)(A + r * K + kg);
      } else {
        if (kg < H) av = *(const float4*)(A + r * H + kg);
        else        av = *(const float4*)(hg + batch[r] * H + (kg - H));
      }
    }
    As[am][ak + 0] = av.x; As[am][ak + 1] = av.y;
    As[am][ak + 2] = av.z; As[am][ak + 3] = av.w;
    float4 wv = *(const float4*)(W + (k0 + bk) * NC + colBase + bc);
    Bs[bk][bc + 0] = wv.x; Bs[bk][bc + 1] = wv.y;
    Bs[bk][bc + 2] = wv.z; Bs[bk][bc + 3] = wv.w;
    __syncthreads();
    #pragma unroll
    for (int kk = 0; kk < 16; ++kk){
      float a0 = As[ty * 4 + 0][kk];
      float a1 = As[ty * 4 + 1][kk];
      float a2 = As[ty * 4 + 2][kk];
      float a3 = As[ty * 4 + 3][kk];
      float b0 = Bs[kk][tx * 4 + 0];
      float b1 = Bs[kk][tx * 4 + 1];
      float b2 = Bs[kk][tx * 4 + 2];
      float b3 = Bs[kk][tx * 4 + 3];
      acc[0][0] += a0 * b0; acc[0][1] += a0 * b1; acc[0][2] += a0 * b2; acc[0][3] += a0 * b3;
      acc[1][0] += a1 * b0; acc[1][1] += a1 * b1; acc[1][2] += a1 * b2; acc[1][3] += a1 * b3;
      acc[2][0] += a2 * b0; acc[2][1] += a2 * b1; acc[2][2] += a2 * b2; acc[2][3] += a2 * b3;
      acc[3][0] += a3 * b0; acc[3][1] += a3 * b1; acc[3][2] += a3 * b2; acc[3][3] += a3 * b3;
    }
    __syncthreads();
  }
  #pragma unroll
  for (int i = 0; i < 4; ++i){
    int r = rowBase + ty * 4 + i;
    if (r >= N) continue;
    #pragma unroll
    for (int j = 0; j < 4; ++j){
      int cidx = colBase + tx * 4 + j;
      float v = acc[i][j] + bias[cidx];
      if (SMODE == 0){
        out[r * NC + cidx] = v;
      } else {
        if (cidx < 64) outsplit[r * 64 + cidx] = v;
        else           outsplit[(size_t)N * 64 + r * 64 + (cidx - 64)] = v;
      }
    }
  }
}

} // namespace

extern "C" void kernel_launch(void* const* d_in, const int* in_sizes, int n_in,
                              void* d_out, int out_size, void* d_ws, size_t ws_size,
                              hipStream_t stream){
  const int* node_type = (const int*)d_in[0];
  const int* edge_type = (const int*)d_in[1];
  const int* src       = (const int*)d_in[2];
  const int* dst       = src + E;
  const int* batch     = (const int*)d_in[3];
  const float* nemb = (const float*)d_in[4];
  const float* eemb = (const float*)d_in[5];
  const float* gs[3] = {(const float*)d_in[6], (const float*)d_in[8], (const float*)d_in[10]};
  const float* bs[3] = {(const float*)d_in[7], (const float*)d_in[9], (const float*)d_in[11]};
  const float* go1 = (const float*)d_in[12]; const float* bo1 = (const float*)d_in[13];
  const float* go2 = (const float*)d_in[14]; const float* bo2 = (const float*)d_in[15];
  const float* W1 = (const float*)d_in[16]; const float* B1 = (const float*)d_in[17];
  const float* W2 = (const float*)d_in[18]; const float* B2 = (const float*)d_in[19];
  const float* W3 = (const float*)d_in[20]; const float* B3 = (const float*)d_in[21];
  float* outf = (float*)d_out;

  float* ws   = (float*)d_ws;
  float* x    = ws;                           // [N,H]
  float* agg  = x   + (size_t)N * H;          // [N,H]
  float* hg   = agg + (size_t)N * H;          // [G,H]
  float* stats = hg + (size_t)G * H;          // sums|sumsq|a|c
  float* sums = stats, *sumsq = stats + 256, *aArr = stats + 512, *cArr = stats + 768;
  int* cnt    = (int*)(stats + 1024);         // [N]
  int* off    = cnt + N;                      // [N+1]
  int* cur    = off + N + 1;                  // [N]
  int2* edges_s = (int2*)(cur + N + 1);       // [E] (src, et) sorted by dst; +1 keeps 8B align
  // total ws: ~105.6 MB

  // ---- CSR build (once; reused by all 3 layers) ----
  hipMemsetAsync(cnt, 0, (size_t)N * sizeof(int), stream);
  k_hist<<<(E + 255) / 256, 256, 0, stream>>>(dst, cnt);
  k_scan<<<1, SCAN_T, 0, stream>>>(cnt, off, cur);
  k_fill<<<(E + 255) / 256, 256, 0, stream>>>(src, dst, edge_type, cur, edges_s);

  k_embed<<<(N * 64 + 255) / 256, 256, 0, stream>>>(node_type, nemb, x);

  for (int l = 0; l < 3; ++l){
    k_gather<<<(N * 64 + 255) / 256, 256, 0, stream>>>(x, agg, edges_s, off, eemb);
    hipMemsetAsync(sums, 0, 512 * sizeof(float), stream);
    k_stats<<<512, H, 0, stream>>>(agg, sums, sumsq, H);
    k_bnparams<<<1, H, 0, stream>>>(sums, sumsq, gs[l], bs[l], aArr, cArr);
    if (l < 2)
      k_norm<1><<<(N * H / 4 + 255) / 256, 256, 0, stream>>>(agg, x, aArr, cArr, N * H / 4, H - 1);
    else
      k_norm<0><<<(N * H / 4 + 255) / 256, 256, 0, stream>>>(agg, x, aArr, cArr, N * H / 4, H - 1);
  }

  k_pool_seg<<<G, H, 0, stream>>>(x, batch, hg);

  // GEMM1: [h | hg[batch]] (N,512) @ W1 (512,256) + B1 -> agg
  {
    dim3 grid((N + 63) / 64, 256 / 64);
    k_gemm<1, 0><<<grid, 256, 0, stream>>>(x, hg, batch, W1, B1, agg, nullptr, 512, 256);
  }
  hipMemsetAsync(sums, 0, 512 * sizeof(float), stream);
  k_stats<<<512, 256, 0, stream>>>(agg, sums, sumsq, 256);
  k_bnparams<<<1, 256, 0, stream>>>(sums, sumsq, go1, bo1, aArr, cArr);
  k_norm<1><<<(N * 256 / 4 + 255) / 256, 256, 0, stream>>>(agg, agg, aArr, cArr, N * 256 / 4, 255);

  // GEMM2: Z1 (N,256) @ W2 (256,128) + B2 -> x
  {
    dim3 grid((N + 63) / 64, 128 / 64);
    k_gemm<0, 0><<<grid, 256, 0, stream>>>(agg, nullptr, nullptr, W2, B2, x, nullptr, 256, 128);
  }
  hipMemsetAsync(sums, 0, 512 * sizeof(float), stream);
  k_stats<<<512, 128, 0, stream>>>(x, sums, sumsq, 128);
  k_bnparams<<<1, 128, 0, stream>>>(sums, sumsq, go2, bo2, aArr, cArr);
  k_norm<1><<<(N * 128 / 4 + 255) / 256, 256, 0, stream>>>(x, x, aArr, cArr, N * 128 / 4, 127);

  // GEMM3: Z2 (N,128) @ W3 (128,128) + B3 -> fp32 split store to d_out
  {
    dim3 grid((N + 63) / 64, 128 / 64);
    k_gemm<0, 1><<<grid, 256, 0, stream>>>(x, nullptr, nullptr, W3, B3, nullptr, outf, 128, 128);
  }
}

// Round 6
// 1066.558 us; speedup vs baseline: 3.7342x; 1.5099x over previous
//
#include <hip/hip_runtime.h>
#include <hip/hip_bf16.h>

namespace {

constexpr int N = 50000;
constexpr int E = 300000;
constexpr int G = 256;
constexpr int H = 256;
constexpr float EPS = 1e-5f;
constexpr int SCAN_T = 1024;

// fast softplus: max(z,0) + log(1+exp(-|z|)); arg of exp in (0,1] -> native approx safe
__device__ __forceinline__ float sp(float z){
  return fmaxf(z, 0.f) + __logf(1.f + __expf(-fabsf(z)));
}

// h[i,f] = node_emb_w[node_type[i], f]
__global__ void k_embed(const int* __restrict__ nt, const float* __restrict__ emb,
                        float* __restrict__ x){
  int idx = blockIdx.x * 256 + threadIdx.x;
  if (idx >= N * 64) return;
  int i = idx >> 6, fq = (idx & 63) << 2;
  *(float4*)(x + i * H + fq) = *(const float4*)(emb + nt[i] * H + fq);
}

// ---- CSR build (by dst) ----
__global__ void k_hist(const int* __restrict__ dst, int* __restrict__ cnt){
  int e = blockIdx.x * 256 + threadIdx.x;
  if (e < E) atomicAdd(&cnt[dst[e]], 1);
}

// single-block exclusive scan of cnt[N] -> off[N] (+ off[N]=E), cur = off copy
__global__ void k_scan(const int* __restrict__ cnt, int* __restrict__ off,
                       int* __restrict__ cur){
  __shared__ int part[SCAN_T];
  int t = threadIdx.x;
  const int C = (N + SCAN_T - 1) / SCAN_T;
  int base = t * C;
  int s = 0;
  for (int k = 0; k < C; ++k){
    int i = base + k;
    if (i < N) s += cnt[i];
  }
  part[t] = s;
  __syncthreads();
  for (int d = 1; d < SCAN_T; d <<= 1){
    int v = (t >= d) ? part[t - d] : 0;
    __syncthreads();
    part[t] += v;
    __syncthreads();
  }
  int run = (t == 0) ? 0 : part[t - 1];
  for (int k = 0; k < C; ++k){
    int i = base + k;
    if (i < N){
      int c = cnt[i];
      off[i] = run; cur[i] = run;
      run += c;
    }
  }
  if (t == SCAN_T - 1) off[N] = run;
}

// edges_s[p] = (src, edge_type) sorted by dst
__global__ void k_fill(const int* __restrict__ src, const int* __restrict__ dst,
                       const int* __restrict__ et, int* __restrict__ cur,
                       int2* __restrict__ edges_s){
  int e = blockIdx.x * 256 + threadIdx.x;
  if (e >= E) return;
  int d = dst[e];
  int p = atomicAdd(&cur[d], 1);
  edges_s[p] = make_int2(src[e], et[e]);
}

__device__ __forceinline__ void acc_sp(float4& acc, const float4 xv, const float4 ev){
  acc.x += sp(xv.x + ev.x);
  acc.y += sp(xv.y + ev.y);
  acc.z += sp(xv.z + ev.z);
  acc.w += sp(xv.w + ev.w);
}

// agg[i] = x[i] + sum_{e: dst=i} softplus(x[src_e] + eemb[et_e]); one wave per node.
// Edge loop unrolled x4: issue all 8 row loads before consuming (4 outstanding misses).
__global__ void k_gather(const float* __restrict__ x, float* __restrict__ agg,
                         const int2* __restrict__ edges_s, const int* __restrict__ off,
                         const float* __restrict__ eemb){
  int gt = blockIdx.x * 256 + threadIdx.x;
  int i = gt >> 6;
  if (i >= N) return;
  int fq = (gt & 63) << 2;
  float4 acc = *(const float4*)(x + (size_t)i * H + fq);
  int lo = off[i], hi = off[i + 1];
  int j = lo;
  for (; j + 4 <= hi; j += 4){
    int2 se0 = edges_s[j + 0];
    int2 se1 = edges_s[j + 1];
    int2 se2 = edges_s[j + 2];
    int2 se3 = edges_s[j + 3];
    float4 x0 = *(const float4*)(x + (size_t)se0.x * H + fq);
    float4 x1 = *(const float4*)(x + (size_t)se1.x * H + fq);
    float4 x2 = *(const float4*)(x + (size_t)se2.x * H + fq);
    float4 x3 = *(const float4*)(x + (size_t)se3.x * H + fq);
    float4 e0 = *(const float4*)(eemb + (size_t)se0.y * H + fq);
    float4 e1 = *(const float4*)(eemb + (size_t)se1.y * H + fq);
    float4 e2 = *(const float4*)(eemb + (size_t)se2.y * H + fq);
    float4 e3 = *(const float4*)(eemb + (size_t)se3.y * H + fq);
    acc_sp(acc, x0, e0);
    acc_sp(acc, x1, e1);
    acc_sp(acc, x2, e2);
    acc_sp(acc, x3, e3);
  }
  for (; j < hi; ++j){
    int2 se = edges_s[j];
    float4 xv = *(const float4*)(x + (size_t)se.x * H + fq);
    float4 ev = *(const float4*)(eemb + (size_t)se.y * H + fq);
    acc_sp(acc, xv, ev);
  }
  *(float4*)(agg + (size_t)i * H + fq) = acc;
}

// per-feature sum / sumsq over N rows; blockDim.x == F
__global__ void k_stats(const float* __restrict__ y, float* __restrict__ sums,
                        float* __restrict__ sumsq, int F){
  int f = threadIdx.x;
  float s = 0.f, s2 = 0.f;
  for (int i = blockIdx.x; i < N; i += gridDim.x){
    float v = y[i * F + f];
    s += v; s2 += v * v;
  }
  atomicAdd(&sums[f], s);
  atomicAdd(&sumsq[f], s2);
}

__global__ void k_bnparams(const float* __restrict__ sums, const float* __restrict__ sumsq,
                           const float* __restrict__ gamma, const float* __restrict__ beta,
                           float* __restrict__ a, float* __restrict__ c){
  int f = threadIdx.x;
  float mean = sums[f] * (1.f / N);
  float var = sumsq[f] * (1.f / N) - mean * mean;   // biased var, matches x.var()
  float rstd = rsqrtf(var + EPS);
  float av = gamma[f] * rstd;
  a[f] = av;
  c[f] = beta[f] - mean * av;
}

template<int ACT>
__global__ void k_norm(const float* __restrict__ in, float* __restrict__ out,
                       const float* __restrict__ a, const float* __restrict__ c,
                       int n4, int fmask){
  int idx = blockIdx.x * 256 + threadIdx.x;
  if (idx >= n4) return;
  int base = idx << 2;
  int f = base & fmask;
  float4 v = *(const float4*)(in + base);
  float4 av = *(const float4*)(a + f);
  float4 cv = *(const float4*)(c + f);
  v.x = av.x * v.x + cv.x;
  v.y = av.y * v.y + cv.y;
  v.z = av.z * v.z + cv.z;
  v.w = av.w * v.w + cv.w;
  if (ACT){ v.x = sp(v.x); v.y = sp(v.y); v.z = sp(v.z); v.w = sp(v.w); }
  *(float4*)(out + base) = v;
}

// segmented pool: batch sorted; one block per group, thread = feature
__global__ void k_pool_seg(const float* __restrict__ x, const int* __restrict__ batch,
                           float* __restrict__ hg){
  int g = blockIdx.x;
  int f = threadIdx.x;
  int lo = 0, hi = N;
  while (lo < hi){ int m = (lo + hi) >> 1; if (batch[m] < g) lo = m + 1; else hi = m; }
  int start = lo;
  lo = 0; hi = N;
  while (lo < hi){ int m = (lo + hi) >> 1; if (batch[m] < g + 1) lo = m + 1; else hi = m; }
  int end = lo;
  float s = 0.f;
  for (int i = start; i < end; ++i) s += x[(size_t)i * H + f];
  hg[g * H + f] = s;
}

// Tiled GEMM: [N,K] fp32 x [K,NC] fp32 + bias
// AMODE 0: plain A (lda=K).  AMODE 1: concat loader (K=512, first 256 from A=x, rest hg[batch[r]]).
// SMODE 0: fp32 out [N,NC].  SMODE 1: fp32 split store to d_out (NC=128, halves at 64).
template<int AMODE, int SMODE>
__global__ void k_gemm(const float* __restrict__ A, const float* __restrict__ hg,
                       const int* __restrict__ batch, const float* __restrict__ W,
                       const float* __restrict__ bias, float* __restrict__ out,
                       float* __restrict__ outsplit, int K, int NC){
  __shared__ float As[64][17];
  __shared__ float Bs[16][68];
  int tid = threadIdx.x;
  int tx = tid & 15, ty = tid >> 4;
  int rowBase = blockIdx.x * 64, colBase = blockIdx.y * 64;
  int am = tid >> 2, ak = (tid & 3) << 2;
  int bk = tid >> 4, bc = (tid & 15) << 2;
  float acc[4][4] = {};
  for (int k0 = 0; k0 < K; k0 += 16){
    int r = rowBase + am;
    float4 av = make_float4(0.f, 0.f, 0.f, 0.f);
    if (r < N){
      int kg = k0 + ak;
      if (AMODE == 0){
        av = *(const float4*)(A + r * K + kg);
      } else {
        if (kg < H) av = *(const float4*)(A + r * H + kg);
        else        av = *(const float4*)(hg + batch[r] * H + (kg - H));
      }
    }
    As[am][ak + 0] = av.x; As[am][ak + 1] = av.y;
    As[am][ak + 2] = av.z; As[am][ak + 3] = av.w;
    float4 wv = *(const float4*)(W + (k0 + bk) * NC + colBase + bc);
    Bs[bk][bc + 0] = wv.x; Bs[bk][bc + 1] = wv.y;
    Bs[bk][bc + 2] = wv.z; Bs[bk][bc + 3] = wv.w;
    __syncthreads();
    #pragma unroll
    for (int kk = 0; kk < 16; ++kk){
      float a0 = As[ty * 4 + 0][kk];
      float a1 = As[ty * 4 + 1][kk];
      float a2 = As[ty * 4 + 2][kk];
      float a3 = As[ty * 4 + 3][kk];
      float b0 = Bs[kk][tx * 4 + 0];
      float b1 = Bs[kk][tx * 4 + 1];
      float b2 = Bs[kk][tx * 4 + 2];
      float b3 = Bs[kk][tx * 4 + 3];
      acc[0][0] += a0 * b0; acc[0][1] += a0 * b1; acc[0][2] += a0 * b2; acc[0][3] += a0 * b3;
      acc[1][0] += a1 * b0; acc[1][1] += a1 * b1; acc[1][2] += a1 * b2; acc[1][3] += a1 * b3;
      acc[2][0] += a2 * b0; acc[2][1] += a2 * b1; acc[2][2] += a2 * b2; acc[2][3] += a2 * b3;
      acc[3][0] += a3 * b0; acc[3][1] += a3 * b1; acc[3][2] += a3 * b2; acc[3][3] += a3 * b3;
    }
    __syncthreads();
  }
  #pragma unroll
  for (int i = 0; i < 4; ++i){
    int r = rowBase + ty * 4 + i;
    if (r >= N) continue;
    #pragma unroll
    for (int j = 0; j < 4; ++j){
      int cidx = colBase + tx * 4 + j;
      float v = acc[i][j] + bias[cidx];
      if (SMODE == 0){
        out[r * NC + cidx] = v;
      } else {
        if (cidx < 64) outsplit[r * 64 + cidx] = v;
        else           outsplit[(size_t)N * 64 + r * 64 + (cidx - 64)] = v;
      }
    }
  }
}

} // namespace

extern "C" void kernel_launch(void* const* d_in, const int* in_sizes, int n_in,
                              void* d_out, int out_size, void* d_ws, size_t ws_size,
                              hipStream_t stream){
  const int* node_type = (const int*)d_in[0];
  const int* edge_type = (const int*)d_in[1];
  const int* src       = (const int*)d_in[2];
  const int* dst       = src + E;
  const int* batch     = (const int*)d_in[3];
  const float* nemb = (const float*)d_in[4];
  const float* eemb = (const float*)d_in[5];
  const float* gs[3] = {(const float*)d_in[6], (const float*)d_in[8], (const float*)d_in[10]};
  const float* bs[3] = {(const float*)d_in[7], (const float*)d_in[9], (const float*)d_in[11]};
  const float* go1 = (const float*)d_in[12]; const float* bo1 = (const float*)d_in[13];
  const float* go2 = (const float*)d_in[14]; const float* bo2 = (const float*)d_in[15];
  const float* W1 = (const float*)d_in[16]; const float* B1 = (const float*)d_in[17];
  const float* W2 = (const float*)d_in[18]; const float* B2 = (const float*)d_in[19];
  const float* W3 = (const float*)d_in[20]; const float* B3 = (const float*)d_in[21];
  float* outf = (float*)d_out;

  float* ws   = (float*)d_ws;
  float* x    = ws;                           // [N,H]
  float* agg  = x   + (size_t)N * H;          // [N,H]
  float* hg   = agg + (size_t)N * H;          // [G,H]
  float* stats = hg + (size_t)G * H;          // sums|sumsq|a|c
  float* sums = stats, *sumsq = stats + 256, *aArr = stats + 512, *cArr = stats + 768;
  int* cnt    = (int*)(stats + 1024);         // [N]
  int* off    = cnt + N;                      // [N+1]
  int* cur    = off + N + 1;                  // [N]
  int2* edges_s = (int2*)(cur + N + 1);       // [E] (src, et) sorted by dst

  // ---- CSR build (once; reused by all 3 layers) ----
  hipMemsetAsync(cnt, 0, (size_t)N * sizeof(int), stream);
  k_hist<<<(E + 255) / 256, 256, 0, stream>>>(dst, cnt);
  k_scan<<<1, SCAN_T, 0, stream>>>(cnt, off, cur);
  k_fill<<<(E + 255) / 256, 256, 0, stream>>>(src, dst, edge_type, cur, edges_s);

  k_embed<<<(N * 64 + 255) / 256, 256, 0, stream>>>(node_type, nemb, x);

  for (int l = 0; l < 3; ++l){
    k_gather<<<(N * 64 + 255) / 256, 256, 0, stream>>>(x, agg, edges_s, off, eemb);
    hipMemsetAsync(sums, 0, 512 * sizeof(float), stream);
    k_stats<<<512, H, 0, stream>>>(agg, sums, sumsq, H);
    k_bnparams<<<1, H, 0, stream>>>(sums, sumsq, gs[l], bs[l], aArr, cArr);
    if (l < 2)
      k_norm<1><<<(N * H / 4 + 255) / 256, 256, 0, stream>>>(agg, x, aArr, cArr, N * H / 4, H - 1);
    else
      k_norm<0><<<(N * H / 4 + 255) / 256, 256, 0, stream>>>(agg, x, aArr, cArr, N * H / 4, H - 1);
  }

  k_pool_seg<<<G, H, 0, stream>>>(x, batch, hg);

  // GEMM1: [h | hg[batch]] (N,512) @ W1 (512,256) + B1 -> agg
  {
    dim3 grid((N + 63) / 64, 256 / 64);
    k_gemm<1, 0><<<grid, 256, 0, stream>>>(x, hg, batch, W1, B1, agg, nullptr, 512, 256);
  }
  hipMemsetAsync(sums, 0, 512 * sizeof(float), stream);
  k_stats<<<512, 256, 0, stream>>>(agg, sums, sumsq, 256);
  k_bnparams<<<1, 256, 0, stream>>>(sums, sumsq, go1, bo1, aArr, cArr);
  k_norm<1><<<(N * 256 / 4 + 255) / 256, 256, 0, stream>>>(agg, agg, aArr, cArr, N * 256 / 4, 255);

  // GEMM2: Z1 (N,256) @ W2 (256,128) + B2 -> x
  {
    dim3 grid((N + 63) / 64, 128 / 64);
    k_gemm<0, 0><<<grid, 256, 0, stream>>>(agg, nullptr, nullptr, W2, B2, x, nullptr, 256, 128);
  }
  hipMemsetAsync(sums, 0, 512 * sizeof(float), stream);
  k_stats<<<512, 128, 0, stream>>>(x, sums, sumsq, 128);
  k_bnparams<<<1, 128, 0, stream>>>(sums, sumsq, go2, bo2, aArr, cArr);
  k_norm<1><<<(N * 128 / 4 + 255) / 256, 256, 0, stream>>>(x, x, aArr, cArr, N * 128 / 4, 127);

  // GEMM3: Z2 (N,128) @ W3 (128,128) + B3 -> fp32 split store to d_out
  {
    dim3 grid((N + 63) / 64, 128 / 64);
    k_gemm<0, 1><<<grid, 256, 0, stream>>>(x, nullptr, nullptr, W3, B3, nullptr, outf, 128, 128);
  }
}

// Round 7
// 903.548 us; speedup vs baseline: 4.4079x; 1.1804x over previous
//
#include <hip/hip_runtime.h>
#include <hip/hip_bf16.h>

namespace {

constexpr int N = 50000;
constexpr int E = 300000;
constexpr int G = 256;
constexpr int H = 256;
constexpr float EPS = 1e-5f;
constexpr int SCAN_T = 1024;

typedef unsigned short u16;
typedef __attribute__((ext_vector_type(8))) short bf16x8;
typedef __attribute__((ext_vector_type(4))) float f32x4;

// fast softplus: max(z,0) + log(1+exp(-|z|)); exp arg in [-max,0] -> native safe
__device__ __forceinline__ float sp(float z){
  return fmaxf(z, 0.f) + __logf(1.f + __expf(-fabsf(z)));
}
// fp32 -> bf16 round-to-nearest-even
__device__ __forceinline__ u16 f2b(float f){
  union { float f; unsigned u; } v; v.f = f;
  unsigned r = v.u + 0x7FFF + ((v.u >> 16) & 1);
  return (u16)(r >> 16);
}

// h[i,f] = node_emb_w[node_type[i], f]
__global__ void k_embed(const int* __restrict__ nt, const float* __restrict__ emb,
                        float* __restrict__ x){
  int idx = blockIdx.x * 256 + threadIdx.x;
  if (idx >= N * 64) return;
  int i = idx >> 6, fq = (idx & 63) << 2;
  *(float4*)(x + i * H + fq) = *(const float4*)(emb + nt[i] * H + fq);
}

// ---- CSR build (by dst) ----
__global__ void k_hist(const int* __restrict__ dst, int* __restrict__ cnt){
  int e = blockIdx.x * 256 + threadIdx.x;
  if (e < E) atomicAdd(&cnt[dst[e]], 1);
}

__global__ void k_scan(const int* __restrict__ cnt, int* __restrict__ off,
                       int* __restrict__ cur){
  __shared__ int part[SCAN_T];
  int t = threadIdx.x;
  const int C = (N + SCAN_T - 1) / SCAN_T;
  int base = t * C;
  int s = 0;
  for (int k = 0; k < C; ++k){
    int i = base + k;
    if (i < N) s += cnt[i];
  }
  part[t] = s;
  __syncthreads();
  for (int d = 1; d < SCAN_T; d <<= 1){
    int v = (t >= d) ? part[t - d] : 0;
    __syncthreads();
    part[t] += v;
    __syncthreads();
  }
  int run = (t == 0) ? 0 : part[t - 1];
  for (int k = 0; k < C; ++k){
    int i = base + k;
    if (i < N){
      int c = cnt[i];
      off[i] = run; cur[i] = run;
      run += c;
    }
  }
  if (t == SCAN_T - 1) off[N] = run;
}

__global__ void k_fill(const int* __restrict__ src, const int* __restrict__ dst,
                       const int* __restrict__ et, int* __restrict__ cur,
                       int2* __restrict__ edges_s){
  int e = blockIdx.x * 256 + threadIdx.x;
  if (e >= E) return;
  int d = dst[e];
  int p = atomicAdd(&cur[d], 1);
  edges_s[p] = make_int2(src[e], et[e]);
}

__device__ __forceinline__ void acc_sp(float4& acc, const float4 xv, const float4 ev){
  acc.x += sp(xv.x + ev.x);
  acc.y += sp(xv.y + ev.y);
  acc.z += sp(xv.z + ev.z);
  acc.w += sp(xv.w + ev.w);
}

// agg[i] = x[i] + sum_{e: dst=i} softplus(x[src_e] + eemb[et_e]); one wave per node, x4 unroll
__global__ void k_gather(const float* __restrict__ x, float* __restrict__ agg,
                         const int2* __restrict__ edges_s, const int* __restrict__ off,
                         const float* __restrict__ eemb){
  int gt = blockIdx.x * 256 + threadIdx.x;
  int i = gt >> 6;
  if (i >= N) return;
  int fq = (gt & 63) << 2;
  float4 acc = *(const float4*)(x + (size_t)i * H + fq);
  int lo = off[i], hi = off[i + 1];
  int j = lo;
  for (; j + 4 <= hi; j += 4){
    int2 se0 = edges_s[j + 0];
    int2 se1 = edges_s[j + 1];
    int2 se2 = edges_s[j + 2];
    int2 se3 = edges_s[j + 3];
    float4 x0 = *(const float4*)(x + (size_t)se0.x * H + fq);
    float4 x1 = *(const float4*)(x + (size_t)se1.x * H + fq);
    float4 x2 = *(const float4*)(x + (size_t)se2.x * H + fq);
    float4 x3 = *(const float4*)(x + (size_t)se3.x * H + fq);
    float4 e0 = *(const float4*)(eemb + (size_t)se0.y * H + fq);
    float4 e1 = *(const float4*)(eemb + (size_t)se1.y * H + fq);
    float4 e2 = *(const float4*)(eemb + (size_t)se2.y * H + fq);
    float4 e3 = *(const float4*)(eemb + (size_t)se3.y * H + fq);
    acc_sp(acc, x0, e0);
    acc_sp(acc, x1, e1);
    acc_sp(acc, x2, e2);
    acc_sp(acc, x3, e3);
  }
  for (; j < hi; ++j){
    int2 se = edges_s[j];
    float4 xv = *(const float4*)(x + (size_t)se.x * H + fq);
    float4 ev = *(const float4*)(eemb + (size_t)se.y * H + fq);
    acc_sp(acc, xv, ev);
  }
  *(float4*)(agg + (size_t)i * H + fq) = acc;
}

// per-feature sum / sumsq over N rows; blockDim.x == F
__global__ void k_stats(const float* __restrict__ y, float* __restrict__ sums,
                        float* __restrict__ sumsq, int F){
  int f = threadIdx.x;
  float s = 0.f, s2 = 0.f;
  for (int i = blockIdx.x; i < N; i += gridDim.x){
    float v = y[i * F + f];
    s += v; s2 += v * v;
  }
  atomicAdd(&sums[f], s);
  atomicAdd(&sumsq[f], s2);
}

// BN-apply with inline param derivation. ACT: softplus. WF: write fp32. WB: write bf16.
template<int ACT, int WF, int WB>
__global__ void k_norm(const float* __restrict__ in, float* __restrict__ outf,
                       u16* __restrict__ outb,
                       const float* __restrict__ sums, const float* __restrict__ sumsq,
                       const float* __restrict__ gamma, const float* __restrict__ beta,
                       int n4, int fmask){
  int idx = blockIdx.x * 256 + threadIdx.x;
  if (idx >= n4) return;
  int base = idx << 2;
  int f = base & fmask;
  float4 s = *(const float4*)(sums + f);
  float4 q = *(const float4*)(sumsq + f);
  float4 g = *(const float4*)(gamma + f);
  float4 bt = *(const float4*)(beta + f);
  float4 v = *(const float4*)(in + base);
  const float inv = 1.f / N;
  float m, var, a, c;
  m = s.x * inv; var = q.x * inv - m * m; a = g.x * rsqrtf(var + EPS); c = bt.x - m * a; v.x = a * v.x + c;
  m = s.y * inv; var = q.y * inv - m * m; a = g.y * rsqrtf(var + EPS); c = bt.y - m * a; v.y = a * v.y + c;
  m = s.z * inv; var = q.z * inv - m * m; a = g.z * rsqrtf(var + EPS); c = bt.z - m * a; v.z = a * v.z + c;
  m = s.w * inv; var = q.w * inv - m * m; a = g.w * rsqrtf(var + EPS); c = bt.w - m * a; v.w = a * v.w + c;
  if (ACT){ v.x = sp(v.x); v.y = sp(v.y); v.z = sp(v.z); v.w = sp(v.w); }
  if (WF) *(float4*)(outf + base) = v;
  if (WB){
    ushort4 o; o.x = f2b(v.x); o.y = f2b(v.y); o.z = f2b(v.z); o.w = f2b(v.w);
    *(ushort4*)(outb + base) = o;
  }
}

// segmented pool: batch sorted; one block per group, thread = feature
__global__ void k_pool_seg(const float* __restrict__ x, const int* __restrict__ batch,
                           float* __restrict__ hg){
  int g = blockIdx.x;
  int f = threadIdx.x;
  int lo = 0, hi = N;
  while (lo < hi){ int m = (lo + hi) >> 1; if (batch[m] < g) lo = m + 1; else hi = m; }
  int start = lo;
  lo = 0; hi = N;
  while (lo < hi){ int m = (lo + hi) >> 1; if (batch[m] < g + 1) lo = m + 1; else hi = m; }
  int end = lo;
  float s = 0.f;
  for (int i = start; i < end; ++i) s += x[(size_t)i * H + f];
  hg[g * H + f] = s;
}

// hgW[g][c] = sum_k hg[g][k] * W1[256+k][c] + B1[c]  (folds concat-half of GEMM1 + bias)
__global__ void k_hgw(const float* __restrict__ hg, const float* __restrict__ W1,
                      const float* __restrict__ B1, float* __restrict__ hgW){
  int g = blockIdx.x, c = threadIdx.x;
  float acc = B1[c];
  for (int k = 0; k < H; ++k)
    acc += hg[g * H + k] * W1[(size_t)(H + k) * H + c];
  hgW[g * H + c] = acc;
}

// convert W1-top/W2/W3 to bf16, transposed to [NC, K] row-major
__global__ void k_wconv(const float* __restrict__ W1, const float* __restrict__ W2,
                        const float* __restrict__ W3, u16* __restrict__ Wt1,
                        u16* __restrict__ Wt2, u16* __restrict__ Wt3){
  int idx = blockIdx.x * 256 + threadIdx.x;
  if (idx < 65536){                     // Wt1 [256,256] <- W1[0:256,256]
    int c = idx >> 8, k = idx & 255;
    Wt1[idx] = f2b(W1[(size_t)k * 256 + c]);
  } else if (idx < 98304){              // Wt2 [128,256] <- W2[256,128]
    int j = idx - 65536;
    int c = j >> 8, k = j & 255;
    Wt2[j] = f2b(W2[(size_t)k * 128 + c]);
  } else if (idx < 114688){             // Wt3 [128,128] <- W3[128,128]
    int j = idx - 98304;
    int c = j >> 7, k = j & 127;
    Wt3[j] = f2b(W3[(size_t)k * 128 + c]);
  }
}

// MFMA GEMM: out[N,NC] = A[N,K](bf16) @ Wt[NC,K]^T(bf16) + epilogue.
// MODE 0: += hgW[batch[row]] (fp32 [G,NC] table, bias pre-folded) -> fp32 out
// MODE 1: += bias -> fp32 out
// MODE 2: += bias -> split fp32 store (cols<64 -> out[row*64+c], else out[N*64+row*64+c-64])
// Block = 4 waves; wave handles 16 rows x NC cols. No LDS.
// Fragment layouts per mfma_f32_16x16x32_bf16 (verified m89/m91):
//   A: lane holds A[m=lane&15][k0 + (lane>>4)*8 + j]  (contig 8 bf16 = 16B)
//   B: lane holds B[k0 + (lane>>4)*8 + j][n=lane&15]  -> Wt[n][k-slice] contig 16B
//   D: reg r -> row = (lane>>4)*4 + r, col = lane&15
template<int K, int NC, int MODE>
__global__ void k_mgemm(const u16* __restrict__ Ab, const u16* __restrict__ Wt,
                        const float* __restrict__ epi, const int* __restrict__ batch,
                        float* __restrict__ out){
  constexpr int NT = NC / 16;
  int tid = threadIdx.x;
  int w = tid >> 6, lane = tid & 63;
  int quad = lane >> 4, l15 = lane & 15;
  int rowBase = blockIdx.x * 64 + w * 16;
  int am = rowBase + l15;
  if (am >= N) am = N - 1;              // clamp: A row only affects D row am (not stored)
  const u16* arow = Ab + (size_t)am * K + quad * 8;
  f32x4 acc[NT] = {};
  for (int k0 = 0; k0 < K; k0 += 32){
    bf16x8 a = *(const bf16x8*)(arow + k0);
    #pragma unroll
    for (int nt = 0; nt < NT; ++nt){
      bf16x8 b = *(const bf16x8*)(Wt + (size_t)(nt * 16 + l15) * K + k0 + quad * 8);
      acc[nt] = __builtin_amdgcn_mfma_f32_16x16x32_bf16(a, b, acc[nt], 0, 0, 0);
    }
  }
  #pragma unroll
  for (int r = 0; r < 4; ++r){
    int row = rowBase + quad * 4 + r;
    if (row >= N) continue;
    int g = (MODE == 0) ? batch[row] : 0;
    #pragma unroll
    for (int nt = 0; nt < NT; ++nt){
      int n = nt * 16 + l15;
      float v = acc[nt][r];
      if (MODE == 0){
        v += epi[(size_t)g * NC + n];
        out[(size_t)row * NC + n] = v;
      } else if (MODE == 1){
        v += epi[n];
        out[(size_t)row * NC + n] = v;
      } else {
        v += epi[n];
        if (n < 64) out[(size_t)row * 64 + n] = v;
        else        out[(size_t)N * 64 + (size_t)row * 64 + (n - 64)] = v;
      }
    }
  }
}

} // namespace

extern "C" void kernel_launch(void* const* d_in, const int* in_sizes, int n_in,
                              void* d_out, int out_size, void* d_ws, size_t ws_size,
                              hipStream_t stream){
  const int* node_type = (const int*)d_in[0];
  const int* edge_type = (const int*)d_in[1];
  const int* src       = (const int*)d_in[2];
  const int* dst       = src + E;
  const int* batch     = (const int*)d_in[3];
  const float* nemb = (const float*)d_in[4];
  const float* eemb = (const float*)d_in[5];
  const float* gs[3] = {(const float*)d_in[6], (const float*)d_in[8], (const float*)d_in[10]};
  const float* bs[3] = {(const float*)d_in[7], (const float*)d_in[9], (const float*)d_in[11]};
  const float* go1 = (const float*)d_in[12]; const float* bo1 = (const float*)d_in[13];
  const float* go2 = (const float*)d_in[14]; const float* bo2 = (const float*)d_in[15];
  const float* W1 = (const float*)d_in[16]; const float* B1 = (const float*)d_in[17];
  const float* W2 = (const float*)d_in[18]; const float* B2 = (const float*)d_in[19];
  const float* W3 = (const float*)d_in[20]; const float* B3 = (const float*)d_in[21];
  float* outf = (float*)d_out;

  float* ws   = (float*)d_ws;
  float* x    = ws;                           // [N,256] fp32
  float* agg  = x   + (size_t)N * H;          // [N,256] fp32
  float* hg   = agg + (size_t)N * H;          // [G,256]
  float* hgW  = hg  + (size_t)G * H;          // [G,256]
  float* stats = hgW + (size_t)G * H;         // sums|sumsq (512)
  float* sums = stats, *sumsq = stats + 256;
  int* cnt    = (int*)(stats + 512);          // [N]
  int* off    = cnt + N;                      // [N+1]
  int* cur    = off + N + 1;                  // [N]
  int2* edges_s = (int2*)(cur + N + 1);       // [E]
  u16* zb     = (u16*)(edges_s + E);          // [N,256] bf16 (xb / Z1b / Z2b aliased)
  u16* Wt1    = zb + (size_t)N * H;           // [256,256] bf16
  u16* Wt2    = Wt1 + 65536;                  // [128,256]
  u16* Wt3    = Wt2 + 32768;                  // [128,128]

  // ---- CSR build + weight conversion ----
  hipMemsetAsync(cnt, 0, (size_t)N * sizeof(int), stream);
  k_hist<<<(E + 255) / 256, 256, 0, stream>>>(dst, cnt);
  k_scan<<<1, SCAN_T, 0, stream>>>(cnt, off, cur);
  k_fill<<<(E + 255) / 256, 256, 0, stream>>>(src, dst, edge_type, cur, edges_s);
  k_wconv<<<(114688 + 255) / 256, 256, 0, stream>>>(W1, W2, W3, Wt1, Wt2, Wt3);

  k_embed<<<(N * 64 + 255) / 256, 256, 0, stream>>>(node_type, nemb, x);

  for (int l = 0; l < 3; ++l){
    k_gather<<<(N * 64 + 255) / 256, 256, 0, stream>>>(x, agg, edges_s, off, eemb);
    hipMemsetAsync(sums, 0, 512 * sizeof(float), stream);
    k_stats<<<512, H, 0, stream>>>(agg, sums, sumsq, H);
    if (l < 2)
      k_norm<1, 1, 0><<<(N * 64 + 255) / 256, 256, 0, stream>>>(
          agg, x, nullptr, sums, sumsq, gs[l], bs[l], N * 64, 255);
    else  // layer 3: fp32 x (for pool) + bf16 copy (GEMM1 A)
      k_norm<0, 1, 1><<<(N * 64 + 255) / 256, 256, 0, stream>>>(
          agg, x, zb, sums, sumsq, gs[l], bs[l], N * 64, 255);
  }

  k_pool_seg<<<G, H, 0, stream>>>(x, batch, hg);
  k_hgw<<<G, H, 0, stream>>>(hg, W1, B1, hgW);

  const int gemmGrid = (N + 63) / 64;
  // GEMM1: xb @ W1top + hgW[batch] -> agg (fp32)
  k_mgemm<256, 256, 0><<<gemmGrid, 256, 0, stream>>>(zb, Wt1, hgW, batch, agg);
  hipMemsetAsync(sums, 0, 512 * sizeof(float), stream);
  k_stats<<<512, 256, 0, stream>>>(agg, sums, sumsq, 256);
  k_norm<1, 0, 1><<<(N * 64 + 255) / 256, 256, 0, stream>>>(
      agg, nullptr, zb, sums, sumsq, go1, bo1, N * 64, 255);

  // GEMM2: Z1b @ W2 + B2 -> x (fp32, [N,128])
  k_mgemm<256, 128, 1><<<gemmGrid, 256, 0, stream>>>(zb, Wt2, B2, nullptr, x);
  hipMemsetAsync(sums, 0, 512 * sizeof(float), stream);
  k_stats<<<512, 128, 0, stream>>>(x, sums, sumsq, 128);
  k_norm<1, 0, 1><<<(N * 32 + 255) / 256, 256, 0, stream>>>(
      x, nullptr, zb, sums, sumsq, go2, bo2, N * 32, 127);

  // GEMM3: Z2b @ W3 + B3 -> split fp32 d_out
  k_mgemm<128, 128, 2><<<gemmGrid, 256, 0, stream>>>(zb, Wt3, B3, nullptr, outf);
}

// Round 8
// 789.830 us; speedup vs baseline: 5.0425x; 1.1440x over previous
//
#include <hip/hip_runtime.h>
#include <hip/hip_bf16.h>

namespace {

constexpr int N = 50000;
constexpr int E = 300000;
constexpr int G = 256;
constexpr int H = 256;
constexpr float EPS = 1e-5f;
constexpr int NB = (N + 255) / 256;   // 196 scan blocks

typedef unsigned short u16;
typedef __attribute__((ext_vector_type(8))) short bf16x8;
typedef __attribute__((ext_vector_type(4))) float f32x4;

// fast softplus: max(z,0) + log(1+exp(-|z|)); exp arg in [-max,0] -> native safe
__device__ __forceinline__ float sp(float z){
  return fmaxf(z, 0.f) + __logf(1.f + __expf(-fabsf(z)));
}
// fp32 -> bf16 round-to-nearest-even
__device__ __forceinline__ u16 f2b(float f){
  union { float f; unsigned u; } v; v.f = f;
  unsigned r = v.u + 0x7FFF + ((v.u >> 16) & 1);
  return (u16)(r >> 16);
}

// h[i,f] = node_emb_w[node_type[i], f]
__global__ void k_embed(const int* __restrict__ nt, const float* __restrict__ emb,
                        float* __restrict__ x){
  int idx = blockIdx.x * 256 + threadIdx.x;
  if (idx >= N * 64) return;
  int i = idx >> 6, fq = (idx & 63) << 2;
  *(float4*)(x + i * H + fq) = *(const float4*)(emb + nt[i] * H + fq);
}

// ---- CSR build (by dst) ----
__global__ void k_hist(const int* __restrict__ dst, int* __restrict__ cnt){
  int e = blockIdx.x * 256 + threadIdx.x;
  if (e < E) atomicAdd(&cnt[dst[e]], 1);
}

// 3-pass device-wide exclusive scan of cnt[N] -> off[N] (+off[N]=E), cur=off copy
__global__ void k_scan1(const int* __restrict__ cnt, int* __restrict__ bsum){
  __shared__ int s[256];
  int t = threadIdx.x;
  int i = blockIdx.x * 256 + t;
  s[t] = (i < N) ? cnt[i] : 0;
  __syncthreads();
  for (int d = 128; d > 0; d >>= 1){
    if (t < d) s[t] += s[t + d];
    __syncthreads();
  }
  if (t == 0) bsum[blockIdx.x] = s[0];
}

__global__ void k_scan2(const int* __restrict__ bsum, int* __restrict__ bbase){
  __shared__ int s[256];
  int t = threadIdx.x;
  int orig = (t < NB) ? bsum[t] : 0;
  s[t] = orig;
  __syncthreads();
  for (int d = 1; d < 256; d <<= 1){
    int v = (t >= d) ? s[t - d] : 0;
    __syncthreads();
    s[t] += v;
    __syncthreads();
  }
  bbase[t] = s[t] - orig;   // exclusive
}

__global__ void k_scan3(const int* __restrict__ cnt, const int* __restrict__ bbase,
                        int* __restrict__ off, int* __restrict__ cur){
  __shared__ int s[256];
  int t = threadIdx.x;
  int i = blockIdx.x * 256 + t;
  int v = (i < N) ? cnt[i] : 0;
  s[t] = v;
  __syncthreads();
  for (int d = 1; d < 256; d <<= 1){
    int u = (t >= d) ? s[t - d] : 0;
    __syncthreads();
    s[t] += u;
    __syncthreads();
  }
  int excl = bbase[blockIdx.x] + s[t] - v;
  if (i < N){ off[i] = excl; cur[i] = excl; }
  if (i == N - 1) off[N] = excl + v;   // == E
}

__global__ void k_fill(const int* __restrict__ src, const int* __restrict__ dst,
                       const int* __restrict__ et, int* __restrict__ cur,
                       int2* __restrict__ edges_s){
  int e = blockIdx.x * 256 + threadIdx.x;
  if (e >= E) return;
  int d = dst[e];
  int p = atomicAdd(&cur[d], 1);
  edges_s[p] = make_int2(src[e], et[e]);
}

__device__ __forceinline__ void acc_sp(float4& acc, const float4 xv, const float4 ev){
  acc.x += sp(xv.x + ev.x);
  acc.y += sp(xv.y + ev.y);
  acc.z += sp(xv.z + ev.z);
  acc.w += sp(xv.w + ev.w);
}

// agg[i] = x[i] + sum_{e: dst=i} softplus(x[src_e] + eemb[et_e]); one wave per node, x4 unroll
__global__ void k_gather(const float* __restrict__ x, float* __restrict__ agg,
                         const int2* __restrict__ edges_s, const int* __restrict__ off,
                         const float* __restrict__ eemb){
  int gt = blockIdx.x * 256 + threadIdx.x;
  int i = gt >> 6;
  if (i >= N) return;
  int fq = (gt & 63) << 2;
  float4 acc = *(const float4*)(x + (size_t)i * H + fq);
  int lo = off[i], hi = off[i + 1];
  int j = lo;
  for (; j + 4 <= hi; j += 4){
    int2 se0 = edges_s[j + 0];
    int2 se1 = edges_s[j + 1];
    int2 se2 = edges_s[j + 2];
    int2 se3 = edges_s[j + 3];
    float4 x0 = *(const float4*)(x + (size_t)se0.x * H + fq);
    float4 x1 = *(const float4*)(x + (size_t)se1.x * H + fq);
    float4 x2 = *(const float4*)(x + (size_t)se2.x * H + fq);
    float4 x3 = *(const float4*)(x + (size_t)se3.x * H + fq);
    float4 e0 = *(const float4*)(eemb + (size_t)se0.y * H + fq);
    float4 e1 = *(const float4*)(eemb + (size_t)se1.y * H + fq);
    float4 e2 = *(const float4*)(eemb + (size_t)se2.y * H + fq);
    float4 e3 = *(const float4*)(eemb + (size_t)se3.y * H + fq);
    acc_sp(acc, x0, e0);
    acc_sp(acc, x1, e1);
    acc_sp(acc, x2, e2);
    acc_sp(acc, x3, e3);
  }
  for (; j < hi; ++j){
    int2 se = edges_s[j];
    float4 xv = *(const float4*)(x + (size_t)se.x * H + fq);
    float4 ev = *(const float4*)(eemb + (size_t)se.y * H + fq);
    acc_sp(acc, xv, ev);
  }
  *(float4*)(agg + (size_t)i * H + fq) = acc;
}

// per-feature sum / sumsq over N rows; blockDim.x == F
__global__ void k_stats(const float* __restrict__ y, float* __restrict__ sums,
                        float* __restrict__ sumsq, int F){
  int f = threadIdx.x;
  float s = 0.f, s2 = 0.f;
  for (int i = blockIdx.x; i < N; i += gridDim.x){
    float v = y[i * F + f];
    s += v; s2 += v * v;
  }
  atomicAdd(&sums[f], s);
  atomicAdd(&sumsq[f], s2);
}

// BN-apply with inline param derivation. ACT: softplus. WF: write fp32. WB: write bf16.
template<int ACT, int WF, int WB>
__global__ void k_norm(const float* __restrict__ in, float* __restrict__ outf,
                       u16* __restrict__ outb,
                       const float* __restrict__ sums, const float* __restrict__ sumsq,
                       const float* __restrict__ gamma, const float* __restrict__ beta,
                       int n4, int fmask){
  int idx = blockIdx.x * 256 + threadIdx.x;
  if (idx >= n4) return;
  int base = idx << 2;
  int f = base & fmask;
  float4 s = *(const float4*)(sums + f);
  float4 q = *(const float4*)(sumsq + f);
  float4 g = *(const float4*)(gamma + f);
  float4 bt = *(const float4*)(beta + f);
  float4 v = *(const float4*)(in + base);
  const float inv = 1.f / N;
  float m, var, a, c;
  m = s.x * inv; var = q.x * inv - m * m; a = g.x * rsqrtf(var + EPS); c = bt.x - m * a; v.x = a * v.x + c;
  m = s.y * inv; var = q.y * inv - m * m; a = g.y * rsqrtf(var + EPS); c = bt.y - m * a; v.y = a * v.y + c;
  m = s.z * inv; var = q.z * inv - m * m; a = g.z * rsqrtf(var + EPS); c = bt.z - m * a; v.z = a * v.z + c;
  m = s.w * inv; var = q.w * inv - m * m; a = g.w * rsqrtf(var + EPS); c = bt.w - m * a; v.w = a * v.w + c;
  if (ACT){ v.x = sp(v.x); v.y = sp(v.y); v.z = sp(v.z); v.w = sp(v.w); }
  if (WF) *(float4*)(outf + base) = v;
  if (WB){
    ushort4 o; o.x = f2b(v.x); o.y = f2b(v.y); o.z = f2b(v.z); o.w = f2b(v.w);
    *(ushort4*)(outb + base) = o;
  }
}

// segmented pool: batch sorted; one block per group, thread = feature
__global__ void k_pool_seg(const float* __restrict__ x, const int* __restrict__ batch,
                           float* __restrict__ hg){
  int g = blockIdx.x;
  int f = threadIdx.x;
  int lo = 0, hi = N;
  while (lo < hi){ int m = (lo + hi) >> 1; if (batch[m] < g) lo = m + 1; else hi = m; }
  int start = lo;
  lo = 0; hi = N;
  while (lo < hi){ int m = (lo + hi) >> 1; if (batch[m] < g + 1) lo = m + 1; else hi = m; }
  int end = lo;
  float s = 0.f;
  for (int i = start; i < end; ++i) s += x[(size_t)i * H + f];
  hg[g * H + f] = s;
}

// hgW[g][c] = sum_k hg[g][k] * W1[256+k][c] + B1[c]  (folds concat-half of GEMM1 + bias)
__global__ void k_hgw(const float* __restrict__ hg, const float* __restrict__ W1,
                      const float* __restrict__ B1, float* __restrict__ hgW){
  int g = blockIdx.x, c = threadIdx.x;
  float acc = B1[c];
  for (int k = 0; k < H; ++k)
    acc += hg[g * H + k] * W1[(size_t)(H + k) * H + c];
  hgW[g * H + c] = acc;
}

// convert W1-top/W2/W3 to bf16, transposed to [NC, K] row-major
__global__ void k_wconv(const float* __restrict__ W1, const float* __restrict__ W2,
                        const float* __restrict__ W3, u16* __restrict__ Wt1,
                        u16* __restrict__ Wt2, u16* __restrict__ Wt3){
  int idx = blockIdx.x * 256 + threadIdx.x;
  if (idx < 65536){                     // Wt1 [256,256] <- W1[0:256,256]
    int c = idx >> 8, k = idx & 255;
    Wt1[idx] = f2b(W1[(size_t)k * 256 + c]);
  } else if (idx < 98304){              // Wt2 [128,256] <- W2[256,128]
    int j = idx - 65536;
    int c = j >> 8, k = j & 255;
    Wt2[j] = f2b(W2[(size_t)k * 128 + c]);
  } else if (idx < 114688){             // Wt3 [128,128] <- W3[128,128]
    int j = idx - 98304;
    int c = j >> 7, k = j & 127;
    Wt3[j] = f2b(W3[(size_t)k * 128 + c]);
  }
}

// MFMA GEMM: out[N,NC] = A[N,K](bf16) @ Wt[NC,K]^T(bf16) + epilogue. No LDS.
// MODE 0: += hgW[batch[row]] -> fp32 out; MODE 1: += bias -> fp32 out;
// MODE 2: += bias -> split fp32 store to d_out.
template<int K, int NC, int MODE>
__global__ void k_mgemm(const u16* __restrict__ Ab, const u16* __restrict__ Wt,
                        const float* __restrict__ epi, const int* __restrict__ batch,
                        float* __restrict__ out){
  constexpr int NT = NC / 16;
  int tid = threadIdx.x;
  int w = tid >> 6, lane = tid & 63;
  int quad = lane >> 4, l15 = lane & 15;
  int rowBase = blockIdx.x * 64 + w * 16;
  int am = rowBase + l15;
  if (am >= N) am = N - 1;
  const u16* arow = Ab + (size_t)am * K + quad * 8;
  f32x4 acc[NT] = {};
  for (int k0 = 0; k0 < K; k0 += 32){
    bf16x8 a = *(const bf16x8*)(arow + k0);
    #pragma unroll
    for (int nt = 0; nt < NT; ++nt){
      bf16x8 b = *(const bf16x8*)(Wt + (size_t)(nt * 16 + l15) * K + k0 + quad * 8);
      acc[nt] = __builtin_amdgcn_mfma_f32_16x16x32_bf16(a, b, acc[nt], 0, 0, 0);
    }
  }
  #pragma unroll
  for (int r = 0; r < 4; ++r){
    int row = rowBase + quad * 4 + r;
    if (row >= N) continue;
    int g = (MODE == 0) ? batch[row] : 0;
    #pragma unroll
    for (int nt = 0; nt < NT; ++nt){
      int n = nt * 16 + l15;
      float v = acc[nt][r];
      if (MODE == 0){
        v += epi[(size_t)g * NC + n];
        out[(size_t)row * NC + n] = v;
      } else if (MODE == 1){
        v += epi[n];
        out[(size_t)row * NC + n] = v;
      } else {
        v += epi[n];
        if (n < 64) out[(size_t)row * 64 + n] = v;
        else        out[(size_t)N * 64 + (size_t)row * 64 + (n - 64)] = v;
      }
    }
  }
}

} // namespace

extern "C" void kernel_launch(void* const* d_in, const int* in_sizes, int n_in,
                              void* d_out, int out_size, void* d_ws, size_t ws_size,
                              hipStream_t stream){
  const int* node_type = (const int*)d_in[0];
  const int* edge_type = (const int*)d_in[1];
  const int* src       = (const int*)d_in[2];
  const int* dst       = src + E;
  const int* batch     = (const int*)d_in[3];
  const float* nemb = (const float*)d_in[4];
  const float* eemb = (const float*)d_in[5];
  const float* gs[3] = {(const float*)d_in[6], (const float*)d_in[8], (const float*)d_in[10]};
  const float* bs[3] = {(const float*)d_in[7], (const float*)d_in[9], (const float*)d_in[11]};
  const float* go1 = (const float*)d_in[12]; const float* bo1 = (const float*)d_in[13];
  const float* go2 = (const float*)d_in[14]; const float* bo2 = (const float*)d_in[15];
  const float* W1 = (const float*)d_in[16]; const float* B1 = (const float*)d_in[17];
  const float* W2 = (const float*)d_in[18]; const float* B2 = (const float*)d_in[19];
  const float* W3 = (const float*)d_in[20]; const float* B3 = (const float*)d_in[21];
  float* outf = (float*)d_out;

  float* ws   = (float*)d_ws;
  float* x    = ws;                           // [N,256] fp32
  float* agg  = x   + (size_t)N * H;          // [N,256] fp32
  float* hg   = agg + (size_t)N * H;          // [G,256]
  float* hgW  = hg  + (size_t)G * H;          // [G,256]
  float* stats = hgW + (size_t)G * H;         // sums|sumsq (512)
  float* sums = stats, *sumsq = stats + 256;
  int* cnt    = (int*)(stats + 512);          // [N]
  int* off    = cnt + N;                      // [N+1]
  int* cur    = off + N + 1;                  // [N]
  int* bsum   = cur + N;                      // [256]
  int* bbase  = bsum + 256;                   // [256]
  int2* edges_s = (int2*)(bbase + 256);       // [E]
  u16* zb     = (u16*)(edges_s + E);          // [N,256] bf16 (xb / Z1b / Z2b aliased)
  u16* Wt1    = zb + (size_t)N * H;           // [256,256] bf16
  u16* Wt2    = Wt1 + 65536;                  // [128,256]
  u16* Wt3    = Wt2 + 32768;                  // [128,128]

  // ---- CSR build + weight conversion ----
  hipMemsetAsync(cnt, 0, (size_t)N * sizeof(int), stream);
  k_hist<<<(E + 255) / 256, 256, 0, stream>>>(dst, cnt);
  k_scan1<<<NB, 256, 0, stream>>>(cnt, bsum);
  k_scan2<<<1, 256, 0, stream>>>(bsum, bbase);
  k_scan3<<<NB, 256, 0, stream>>>(cnt, bbase, off, cur);
  k_fill<<<(E + 255) / 256, 256, 0, stream>>>(src, dst, edge_type, cur, edges_s);
  k_wconv<<<(114688 + 255) / 256, 256, 0, stream>>>(W1, W2, W3, Wt1, Wt2, Wt3);

  k_embed<<<(N * 64 + 255) / 256, 256, 0, stream>>>(node_type, nemb, x);

  for (int l = 0; l < 3; ++l){
    k_gather<<<(N * 64 + 255) / 256, 256, 0, stream>>>(x, agg, edges_s, off, eemb);
    hipMemsetAsync(sums, 0, 512 * sizeof(float), stream);
    k_stats<<<512, H, 0, stream>>>(agg, sums, sumsq, H);
    if (l < 2)
      k_norm<1, 1, 0><<<(N * 64 + 255) / 256, 256, 0, stream>>>(
          agg, x, nullptr, sums, sumsq, gs[l], bs[l], N * 64, 255);
    else
      k_norm<0, 1, 1><<<(N * 64 + 255) / 256, 256, 0, stream>>>(
          agg, x, zb, sums, sumsq, gs[l], bs[l], N * 64, 255);
  }

  k_pool_seg<<<G, H, 0, stream>>>(x, batch, hg);
  k_hgw<<<G, H, 0, stream>>>(hg, W1, B1, hgW);

  const int gemmGrid = (N + 63) / 64;
  // GEMM1: xb @ W1top + hgW[batch] -> agg (fp32)
  k_mgemm<256, 256, 0><<<gemmGrid, 256, 0, stream>>>(zb, Wt1, hgW, batch, agg);
  hipMemsetAsync(sums, 0, 512 * sizeof(float), stream);
  k_stats<<<512, 256, 0, stream>>>(agg, sums, sumsq, 256);
  k_norm<1, 0, 1><<<(N * 64 + 255) / 256, 256, 0, stream>>>(
      agg, nullptr, zb, sums, sumsq, go1, bo1, N * 64, 255);

  // GEMM2: Z1b @ W2 + B2 -> x (fp32, [N,128])
  k_mgemm<256, 128, 1><<<gemmGrid, 256, 0, stream>>>(zb, Wt2, B2, nullptr, x);
  hipMemsetAsync(sums, 0, 512 * sizeof(float), stream);
  k_stats<<<512, 128, 0, stream>>>(x, sums, sumsq, 128);
  k_norm<1, 0, 1><<<(N * 32 + 255) / 256, 256, 0, stream>>>(
      x, nullptr, zb, sums, sumsq, go2, bo2, N * 32, 127);

  // GEMM3: Z2b @ W3 + B3 -> split fp32 d_out
  k_mgemm<128, 128, 2><<<gemmGrid, 256, 0, stream>>>(zb, Wt3, B3, nullptr, outf);
}

// Round 9
// 744.539 us; speedup vs baseline: 5.3492x; 1.0608x over previous
//
#include <hip/hip_runtime.h>
#include <hip/hip_bf16.h>

namespace {

constexpr int N = 50000;
constexpr int E = 300000;
constexpr int G = 256;
constexpr int H = 256;
constexpr float EPS = 1e-5f;
constexpr int NB = (N + 255) / 256;   // 196 scan blocks

typedef unsigned short u16;
typedef __attribute__((ext_vector_type(8))) short bf16x8;
typedef __attribute__((ext_vector_type(4))) float f32x4;

// fast softplus: max(z,0) + log(1+exp(-|z|)); exp arg in [-max,0] -> native safe
__device__ __forceinline__ float sp(float z){
  return fmaxf(z, 0.f) + __logf(1.f + __expf(-fabsf(z)));
}
// fp32 -> bf16 round-to-nearest-even
__device__ __forceinline__ u16 f2b(float f){
  union { float f; unsigned u; } v; v.f = f;
  unsigned r = v.u + 0x7FFF + ((v.u >> 16) & 1);
  return (u16)(r >> 16);
}

// h[i,f] = node_emb_w[node_type[i], f]
__global__ void k_embed(const int* __restrict__ nt, const float* __restrict__ emb,
                        float* __restrict__ x){
  int idx = blockIdx.x * 256 + threadIdx.x;
  if (idx >= N * 64) return;
  int i = idx >> 6, fq = (idx & 63) << 2;
  *(float4*)(x + i * H + fq) = *(const float4*)(emb + nt[i] * H + fq);
}

// ---- CSR build (by dst) ----
__global__ void k_hist(const int* __restrict__ dst, int* __restrict__ cnt){
  int e = blockIdx.x * 256 + threadIdx.x;
  if (e < E) atomicAdd(&cnt[dst[e]], 1);
}

// 3-pass device-wide exclusive scan of cnt[N] -> off[N] (+off[N]=E), cur=off copy
__global__ void k_scan1(const int* __restrict__ cnt, int* __restrict__ bsum){
  __shared__ int s[256];
  int t = threadIdx.x;
  int i = blockIdx.x * 256 + t;
  s[t] = (i < N) ? cnt[i] : 0;
  __syncthreads();
  for (int d = 128; d > 0; d >>= 1){
    if (t < d) s[t] += s[t + d];
    __syncthreads();
  }
  if (t == 0) bsum[blockIdx.x] = s[0];
}

__global__ void k_scan2(const int* __restrict__ bsum, int* __restrict__ bbase){
  __shared__ int s[256];
  int t = threadIdx.x;
  int orig = (t < NB) ? bsum[t] : 0;
  s[t] = orig;
  __syncthreads();
  for (int d = 1; d < 256; d <<= 1){
    int v = (t >= d) ? s[t - d] : 0;
    __syncthreads();
    s[t] += v;
    __syncthreads();
  }
  bbase[t] = s[t] - orig;   // exclusive
}

__global__ void k_scan3(const int* __restrict__ cnt, const int* __restrict__ bbase,
                        int* __restrict__ off, int* __restrict__ cur){
  __shared__ int s[256];
  int t = threadIdx.x;
  int i = blockIdx.x * 256 + t;
  int v = (i < N) ? cnt[i] : 0;
  s[t] = v;
  __syncthreads();
  for (int d = 1; d < 256; d <<= 1){
    int u = (t >= d) ? s[t - d] : 0;
    __syncthreads();
    s[t] += u;
    __syncthreads();
  }
  int excl = bbase[blockIdx.x] + s[t] - v;
  if (i < N){ off[i] = excl; cur[i] = excl; }
  if (i == N - 1) off[N] = excl + v;   // == E
}

__global__ void k_fill(const int* __restrict__ src, const int* __restrict__ dst,
                       const int* __restrict__ et, int* __restrict__ cur,
                       int2* __restrict__ edges_s){
  int e = blockIdx.x * 256 + threadIdx.x;
  if (e >= E) return;
  int d = dst[e];
  int p = atomicAdd(&cur[d], 1);
  edges_s[p] = make_int2(src[e], et[e]);
}

__device__ __forceinline__ void acc_sp(float4& acc, const float4 xv, const float4 ev){
  acc.x += sp(xv.x + ev.x);
  acc.y += sp(xv.y + ev.y);
  acc.z += sp(xv.z + ev.z);
  acc.w += sp(xv.w + ev.w);
}

// agg[i] = x[i] + sum_{e: dst=i} softplus(x[src_e] + eemb[et_e]); one wave per node, x4 unroll
__global__ void k_gather(const float* __restrict__ x, float* __restrict__ agg,
                         const int2* __restrict__ edges_s, const int* __restrict__ off,
                         const float* __restrict__ eemb){
  int gt = blockIdx.x * 256 + threadIdx.x;
  int i = gt >> 6;
  if (i >= N) return;
  int fq = (gt & 63) << 2;
  float4 acc = *(const float4*)(x + (size_t)i * H + fq);
  int lo = off[i], hi = off[i + 1];
  int j = lo;
  for (; j + 4 <= hi; j += 4){
    int2 se0 = edges_s[j + 0];
    int2 se1 = edges_s[j + 1];
    int2 se2 = edges_s[j + 2];
    int2 se3 = edges_s[j + 3];
    float4 x0 = *(const float4*)(x + (size_t)se0.x * H + fq);
    float4 x1 = *(const float4*)(x + (size_t)se1.x * H + fq);
    float4 x2 = *(const float4*)(x + (size_t)se2.x * H + fq);
    float4 x3 = *(const float4*)(x + (size_t)se3.x * H + fq);
    float4 e0 = *(const float4*)(eemb + (size_t)se0.y * H + fq);
    float4 e1 = *(const float4*)(eemb + (size_t)se1.y * H + fq);
    float4 e2 = *(const float4*)(eemb + (size_t)se2.y * H + fq);
    float4 e3 = *(const float4*)(eemb + (size_t)se3.y * H + fq);
    acc_sp(acc, x0, e0);
    acc_sp(acc, x1, e1);
    acc_sp(acc, x2, e2);
    acc_sp(acc, x3, e3);
  }
  for (; j < hi; ++j){
    int2 se = edges_s[j];
    float4 xv = *(const float4*)(x + (size_t)se.x * H + fq);
    float4 ev = *(const float4*)(eemb + (size_t)se.y * H + fq);
    acc_sp(acc, xv, ev);
  }
  *(float4*)(agg + (size_t)i * H + fq) = acc;
}

// per-feature sum / sumsq over N rows; blockDim.x == F
__global__ void k_stats(const float* __restrict__ y, float* __restrict__ sums,
                        float* __restrict__ sumsq, int F){
  int f = threadIdx.x;
  float s = 0.f, s2 = 0.f;
  for (int i = blockIdx.x; i < N; i += gridDim.x){
    float v = y[i * F + f];
    s += v; s2 += v * v;
  }
  atomicAdd(&sums[f], s);
  atomicAdd(&sumsq[f], s2);
}

// BN-apply with inline param derivation. ACT: softplus. WF: write fp32. WB: write bf16.
template<int ACT, int WF, int WB>
__global__ void k_norm(const float* __restrict__ in, float* __restrict__ outf,
                       u16* __restrict__ outb,
                       const float* __restrict__ sums, const float* __restrict__ sumsq,
                       const float* __restrict__ gamma, const float* __restrict__ beta,
                       int n4, int fmask){
  int idx = blockIdx.x * 256 + threadIdx.x;
  if (idx >= n4) return;
  int base = idx << 2;
  int f = base & fmask;
  float4 s = *(const float4*)(sums + f);
  float4 q = *(const float4*)(sumsq + f);
  float4 g = *(const float4*)(gamma + f);
  float4 bt = *(const float4*)(beta + f);
  float4 v = *(const float4*)(in + base);
  const float inv = 1.f / N;
  float m, var, a, c;
  m = s.x * inv; var = q.x * inv - m * m; a = g.x * rsqrtf(var + EPS); c = bt.x - m * a; v.x = a * v.x + c;
  m = s.y * inv; var = q.y * inv - m * m; a = g.y * rsqrtf(var + EPS); c = bt.y - m * a; v.y = a * v.y + c;
  m = s.z * inv; var = q.z * inv - m * m; a = g.z * rsqrtf(var + EPS); c = bt.z - m * a; v.z = a * v.z + c;
  m = s.w * inv; var = q.w * inv - m * m; a = g.w * rsqrtf(var + EPS); c = bt.w - m * a; v.w = a * v.w + c;
  if (ACT){ v.x = sp(v.x); v.y = sp(v.y); v.z = sp(v.z); v.w = sp(v.w); }
  if (WF) *(float4*)(outf + base) = v;
  if (WB){
    ushort4 o; o.x = f2b(v.x); o.y = f2b(v.y); o.z = f2b(v.z); o.w = f2b(v.w);
    *(ushort4*)(outb + base) = o;
  }
}

// segmented pool: batch sorted; one block per group, thread = feature
__global__ void k_pool_seg(const float* __restrict__ x, const int* __restrict__ batch,
                           float* __restrict__ hg){
  int g = blockIdx.x;
  int f = threadIdx.x;
  int lo = 0, hi = N;
  while (lo < hi){ int m = (lo + hi) >> 1; if (batch[m] < g) lo = m + 1; else hi = m; }
  int start = lo;
  lo = 0; hi = N;
  while (lo < hi){ int m = (lo + hi) >> 1; if (batch[m] < g + 1) lo = m + 1; else hi = m; }
  int end = lo;
  float s = 0.f;
  for (int i = start; i < end; ++i) s += x[(size_t)i * H + f];
  hg[g * H + f] = s;
}

// hgW[g][c] = sum_k hg[g][k] * W1[256+k][c] + B1[c]  (folds concat-half of GEMM1 + bias)
__global__ void k_hgw(const float* __restrict__ hg, const float* __restrict__ W1,
                      const float* __restrict__ B1, float* __restrict__ hgW){
  int g = blockIdx.x, c = threadIdx.x;
  float acc = B1[c];
  for (int k = 0; k < H; ++k)
    acc += hg[g * H + k] * W1[(size_t)(H + k) * H + c];
  hgW[g * H + c] = acc;
}

// convert W1-top/W2/W3 to bf16, transposed to [NC, K] row-major
__global__ void k_wconv(const float* __restrict__ W1, const float* __restrict__ W2,
                        const float* __restrict__ W3, u16* __restrict__ Wt1,
                        u16* __restrict__ Wt2, u16* __restrict__ Wt3){
  int idx = blockIdx.x * 256 + threadIdx.x;
  if (idx < 65536){                     // Wt1 [256,256] <- W1[0:256,256]
    int c = idx >> 8, k = idx & 255;
    Wt1[idx] = f2b(W1[(size_t)k * 256 + c]);
  } else if (idx < 98304){              // Wt2 [128,256] <- W2[256,128]
    int j = idx - 65536;
    int c = j >> 8, k = j & 255;
    Wt2[j] = f2b(W2[(size_t)k * 128 + c]);
  } else if (idx < 114688){             // Wt3 [128,128] <- W3[128,128]
    int j = idx - 98304;
    int c = j >> 7, k = j & 127;
    Wt3[j] = f2b(W3[(size_t)k * 128 + c]);
  }
}

// MFMA GEMM, 64x64 per wave: out[N,NC] = A[N,K](bf16) @ Wt[NC,K]^T(bf16) + epilogue.
// Wave computes 4 row-tiles x 4 col-tiles of 16x16 (acc[4][4]); per K-step:
// 8 x 16B loads feed 16 MFMAs. WR row-waves x (4/WR) col-waves per block.
// MODE 0: += hgW[batch[row]] -> fp32 out; MODE 1: += bias -> fp32 out;
// MODE 2: += bias -> split fp32 store to d_out.
template<int K, int NC, int MODE, int WR>
__global__ void k_mgemm(const u16* __restrict__ Ab, const u16* __restrict__ Wt,
                        const float* __restrict__ epi, const int* __restrict__ batch,
                        float* __restrict__ out){
  constexpr int WC = 4 / WR;
  int tid = threadIdx.x;
  int w = tid >> 6, lane = tid & 63;
  int quad = lane >> 4, l15 = lane & 15;
  int wr = w / WC, wc = w % WC;
  int rowBase = blockIdx.x * (WR * 64) + wr * 64;
  int colBase = wc * 64;
  const u16* arow[4];
  #pragma unroll
  for (int t = 0; t < 4; ++t){
    int am = rowBase + t * 16 + l15;
    if (am >= N) am = N - 1;            // clamp; stores are guarded
    arow[t] = Ab + (size_t)am * K + quad * 8;
  }
  const u16* brow[4];
  #pragma unroll
  for (int u = 0; u < 4; ++u)
    brow[u] = Wt + (size_t)(colBase + u * 16 + l15) * K + quad * 8;
  f32x4 acc[4][4] = {};
  for (int k0 = 0; k0 < K; k0 += 32){
    bf16x8 a[4], b[4];
    #pragma unroll
    for (int t = 0; t < 4; ++t) a[t] = *(const bf16x8*)(arow[t] + k0);
    #pragma unroll
    for (int u = 0; u < 4; ++u) b[u] = *(const bf16x8*)(brow[u] + k0);
    #pragma unroll
    for (int t = 0; t < 4; ++t)
      #pragma unroll
      for (int u = 0; u < 4; ++u)
        acc[t][u] = __builtin_amdgcn_mfma_f32_16x16x32_bf16(a[t], b[u], acc[t][u], 0, 0, 0);
  }
  #pragma unroll
  for (int t = 0; t < 4; ++t){
    #pragma unroll
    for (int r = 0; r < 4; ++r){
      int row = rowBase + t * 16 + quad * 4 + r;
      if (row >= N) continue;
      int g = (MODE == 0) ? batch[row] : 0;
      #pragma unroll
      for (int u = 0; u < 4; ++u){
        int n = colBase + u * 16 + l15;
        float v = acc[t][u][r];
        if (MODE == 0){
          v += epi[(size_t)g * NC + n];
          out[(size_t)row * NC + n] = v;
        } else if (MODE == 1){
          v += epi[n];
          out[(size_t)row * NC + n] = v;
        } else {
          v += epi[n];
          if (n < 64) out[(size_t)row * 64 + n] = v;
          else        out[(size_t)N * 64 + (size_t)row * 64 + (n - 64)] = v;
        }
      }
    }
  }
}

} // namespace

extern "C" void kernel_launch(void* const* d_in, const int* in_sizes, int n_in,
                              void* d_out, int out_size, void* d_ws, size_t ws_size,
                              hipStream_t stream){
  const int* node_type = (const int*)d_in[0];
  const int* edge_type = (const int*)d_in[1];
  const int* src       = (const int*)d_in[2];
  const int* dst       = src + E;
  const int* batch     = (const int*)d_in[3];
  const float* nemb = (const float*)d_in[4];
  const float* eemb = (const float*)d_in[5];
  const float* gs[3] = {(const float*)d_in[6], (const float*)d_in[8], (const float*)d_in[10]};
  const float* bs[3] = {(const float*)d_in[7], (const float*)d_in[9], (const float*)d_in[11]};
  const float* go1 = (const float*)d_in[12]; const float* bo1 = (const float*)d_in[13];
  const float* go2 = (const float*)d_in[14]; const float* bo2 = (const float*)d_in[15];
  const float* W1 = (const float*)d_in[16]; const float* B1 = (const float*)d_in[17];
  const float* W2 = (const float*)d_in[18]; const float* B2 = (const float*)d_in[19];
  const float* W3 = (const float*)d_in[20]; const float* B3 = (const float*)d_in[21];
  float* outf = (float*)d_out;

  float* ws   = (float*)d_ws;
  float* x    = ws;                           // [N,256] fp32
  float* agg  = x   + (size_t)N * H;          // [N,256] fp32
  float* hg   = agg + (size_t)N * H;          // [G,256]
  float* hgW  = hg  + (size_t)G * H;          // [G,256]
  float* stats = hgW + (size_t)G * H;         // sums|sumsq (512)
  float* sums = stats, *sumsq = stats + 256;
  int* cnt    = (int*)(stats + 512);          // [N]
  int* off    = cnt + N;                      // [N+1]
  int* cur    = off + N + 1;                  // [N]
  int* bsum   = cur + N;                      // [256]
  int* bbase  = bsum + 256;                   // [256]
  int2* edges_s = (int2*)(bbase + 256);       // [E]
  u16* zb     = (u16*)(edges_s + E);          // [N,256] bf16 (xb / Z1b / Z2b aliased)
  u16* Wt1    = zb + (size_t)N * H;           // [256,256] bf16
  u16* Wt2    = Wt1 + 65536;                  // [128,256]
  u16* Wt3    = Wt2 + 32768;                  // [128,128]

  // ---- CSR build + weight conversion ----
  hipMemsetAsync(cnt, 0, (size_t)N * sizeof(int), stream);
  k_hist<<<(E + 255) / 256, 256, 0, stream>>>(dst, cnt);
  k_scan1<<<NB, 256, 0, stream>>>(cnt, bsum);
  k_scan2<<<1, 256, 0, stream>>>(bsum, bbase);
  k_scan3<<<NB, 256, 0, stream>>>(cnt, bbase, off, cur);
  k_fill<<<(E + 255) / 256, 256, 0, stream>>>(src, dst, edge_type, cur, edges_s);
  k_wconv<<<(114688 + 255) / 256, 256, 0, stream>>>(W1, W2, W3, Wt1, Wt2, Wt3);

  k_embed<<<(N * 64 + 255) / 256, 256, 0, stream>>>(node_type, nemb, x);

  for (int l = 0; l < 3; ++l){
    k_gather<<<(N * 64 + 255) / 256, 256, 0, stream>>>(x, agg, edges_s, off, eemb);
    hipMemsetAsync(sums, 0, 512 * sizeof(float), stream);
    k_stats<<<512, H, 0, stream>>>(agg, sums, sumsq, H);
    if (l < 2)
      k_norm<1, 1, 0><<<(N * 64 + 255) / 256, 256, 0, stream>>>(
          agg, x, nullptr, sums, sumsq, gs[l], bs[l], N * 64, 255);
    else
      k_norm<0, 1, 1><<<(N * 64 + 255) / 256, 256, 0, stream>>>(
          agg, x, zb, sums, sumsq, gs[l], bs[l], N * 64, 255);
  }

  k_pool_seg<<<G, H, 0, stream>>>(x, batch, hg);
  k_hgw<<<G, H, 0, stream>>>(hg, W1, B1, hgW);

  // GEMM1: xb @ W1top + hgW[batch] -> agg (fp32); 64x256 blocks
  k_mgemm<256, 256, 0, 1><<<(N + 63) / 64, 256, 0, stream>>>(zb, Wt1, hgW, batch, agg);
  hipMemsetAsync(sums, 0, 512 * sizeof(float), stream);
  k_stats<<<512, 256, 0, stream>>>(agg, sums, sumsq, 256);
  k_norm<1, 0, 1><<<(N * 64 + 255) / 256, 256, 0, stream>>>(
      agg, nullptr, zb, sums, sumsq, go1, bo1, N * 64, 255);

  // GEMM2: Z1b @ W2 + B2 -> x (fp32, [N,128]); 128x128 blocks
  k_mgemm<256, 128, 1, 2><<<(N + 127) / 128, 256, 0, stream>>>(zb, Wt2, B2, nullptr, x);
  hipMemsetAsync(sums, 0, 512 * sizeof(float), stream);
  k_stats<<<512, 128, 0, stream>>>(x, sums, sumsq, 128);
  k_norm<1, 0, 1><<<(N * 32 + 255) / 256, 256, 0, stream>>>(
      x, nullptr, zb, sums, sumsq, go2, bo2, N * 32, 127);

  // GEMM3: Z2b @ W3 + B3 -> split fp32 d_out; 128x128 blocks
  k_mgemm<128, 128, 2, 2><<<(N + 127) / 128, 256, 0, stream>>>(zb, Wt3, B3, nullptr, outf);
}

// Round 10
// 684.916 us; speedup vs baseline: 5.8149x; 1.0871x over previous
//
#include <hip/hip_runtime.h>
#include <hip/hip_bf16.h>

namespace {

constexpr int N = 50000;
constexpr int E = 300000;
constexpr int G = 256;
constexpr int H = 256;
constexpr float EPS = 1e-5f;
constexpr int NB = (N + 255) / 256;   // 196 scan blocks
constexpr int POOL_S = 8;             // row-slices per group in pool

typedef unsigned short u16;
typedef __attribute__((ext_vector_type(8))) short bf16x8;
typedef __attribute__((ext_vector_type(4))) float f32x4;

// fast softplus: max(z,0) + log(1+exp(-|z|)); exp arg in [-max,0] -> native safe
__device__ __forceinline__ float sp(float z){
  return fmaxf(z, 0.f) + __logf(1.f + __expf(-fabsf(z)));
}
// fp32 -> bf16 round-to-nearest-even
__device__ __forceinline__ u16 f2b(float f){
  union { float f; unsigned u; } v; v.f = f;
  unsigned r = v.u + 0x7FFF + ((v.u >> 16) & 1);
  return (u16)(r >> 16);
}
__device__ __forceinline__ float b2f(u16 u){
  union { unsigned i; float f; } v; v.i = ((unsigned)u) << 16; return v.f;
}
__device__ __forceinline__ float4 b2f4(ushort4 u){
  return make_float4(b2f(u.x), b2f(u.y), b2f(u.z), b2f(u.w));
}

// xb[i,f] = bf16(node_emb_w[node_type[i], f])
__global__ void k_embed(const int* __restrict__ nt, const float* __restrict__ emb,
                        u16* __restrict__ xb){
  int idx = blockIdx.x * 256 + threadIdx.x;
  if (idx >= N * 64) return;
  int i = idx >> 6, fq = (idx & 63) << 2;
  float4 v = *(const float4*)(emb + (size_t)nt[i] * H + fq);
  ushort4 o; o.x = f2b(v.x); o.y = f2b(v.y); o.z = f2b(v.z); o.w = f2b(v.w);
  *(ushort4*)(xb + (size_t)i * H + fq) = o;
}

// ---- CSR build (by dst) ----
__global__ void k_hist(const int* __restrict__ dst, int* __restrict__ cnt){
  int e = blockIdx.x * 256 + threadIdx.x;
  if (e < E) atomicAdd(&cnt[dst[e]], 1);
}

__global__ void k_scan1(const int* __restrict__ cnt, int* __restrict__ bsum){
  __shared__ int s[256];
  int t = threadIdx.x;
  int i = blockIdx.x * 256 + t;
  s[t] = (i < N) ? cnt[i] : 0;
  __syncthreads();
  for (int d = 128; d > 0; d >>= 1){
    if (t < d) s[t] += s[t + d];
    __syncthreads();
  }
  if (t == 0) bsum[blockIdx.x] = s[0];
}

__global__ void k_scan2(const int* __restrict__ bsum, int* __restrict__ bbase){
  __shared__ int s[256];
  int t = threadIdx.x;
  int orig = (t < NB) ? bsum[t] : 0;
  s[t] = orig;
  __syncthreads();
  for (int d = 1; d < 256; d <<= 1){
    int v = (t >= d) ? s[t - d] : 0;
    __syncthreads();
    s[t] += v;
    __syncthreads();
  }
  bbase[t] = s[t] - orig;   // exclusive
}

__global__ void k_scan3(const int* __restrict__ cnt, const int* __restrict__ bbase,
                        int* __restrict__ off, int* __restrict__ cur){
  __shared__ int s[256];
  int t = threadIdx.x;
  int i = blockIdx.x * 256 + t;
  int v = (i < N) ? cnt[i] : 0;
  s[t] = v;
  __syncthreads();
  for (int d = 1; d < 256; d <<= 1){
    int u = (t >= d) ? s[t - d] : 0;
    __syncthreads();
    s[t] += u;
    __syncthreads();
  }
  int excl = bbase[blockIdx.x] + s[t] - v;
  if (i < N){ off[i] = excl; cur[i] = excl; }
  if (i == N - 1) off[N] = excl + v;   // == E
}

// edges_s[p] = (src*H, et*H) sorted by dst (pre-scaled element offsets)
__global__ void k_fill(const int* __restrict__ src, const int* __restrict__ dst,
                       const int* __restrict__ et, int* __restrict__ cur,
                       int2* __restrict__ edges_s){
  int e = blockIdx.x * 256 + threadIdx.x;
  if (e >= E) return;
  int d = dst[e];
  int p = atomicAdd(&cur[d], 1);
  edges_s[p] = make_int2(src[e] * H, et[e] * H);
}

__device__ __forceinline__ void acc_sp(float4& acc, const float4 xv, const float4 ev){
  acc.x += sp(xv.x + ev.x);
  acc.y += sp(xv.y + ev.y);
  acc.z += sp(xv.z + ev.z);
  acc.w += sp(xv.w + ev.w);
}

// agg[i] = xb[i] + sum_{e: dst=i} softplus(xb[src_e] + eemb[et_e]); one wave/node, x4 unroll
__global__ void k_gather(const u16* __restrict__ xb, float* __restrict__ agg,
                         const int2* __restrict__ edges_s, const int* __restrict__ off,
                         const float* __restrict__ eemb){
  int gt = blockIdx.x * 256 + threadIdx.x;
  int i = gt >> 6;
  if (i >= N) return;
  int fq = (gt & 63) << 2;
  float4 acc = b2f4(*(const ushort4*)(xb + (size_t)i * H + fq));
  int lo = off[i], hi = off[i + 1];
  int j = lo;
  for (; j + 4 <= hi; j += 4){
    int2 se0 = edges_s[j + 0];
    int2 se1 = edges_s[j + 1];
    int2 se2 = edges_s[j + 2];
    int2 se3 = edges_s[j + 3];
    ushort4 r0 = *(const ushort4*)(xb + (size_t)se0.x + fq);
    ushort4 r1 = *(const ushort4*)(xb + (size_t)se1.x + fq);
    ushort4 r2 = *(const ushort4*)(xb + (size_t)se2.x + fq);
    ushort4 r3 = *(const ushort4*)(xb + (size_t)se3.x + fq);
    float4 e0 = *(const float4*)(eemb + (size_t)se0.y + fq);
    float4 e1 = *(const float4*)(eemb + (size_t)se1.y + fq);
    float4 e2 = *(const float4*)(eemb + (size_t)se2.y + fq);
    float4 e3 = *(const float4*)(eemb + (size_t)se3.y + fq);
    acc_sp(acc, b2f4(r0), e0);
    acc_sp(acc, b2f4(r1), e1);
    acc_sp(acc, b2f4(r2), e2);
    acc_sp(acc, b2f4(r3), e3);
  }
  for (; j < hi; ++j){
    int2 se = edges_s[j];
    ushort4 rv = *(const ushort4*)(xb + (size_t)se.x + fq);
    float4 ev = *(const float4*)(eemb + (size_t)se.y + fq);
    acc_sp(acc, b2f4(rv), ev);
  }
  *(float4*)(agg + (size_t)i * H + fq) = acc;
}

// per-feature sum / sumsq over N rows of fp32 y; blockDim.x == F
__global__ void k_stats(const float* __restrict__ y, float* __restrict__ sums,
                        float* __restrict__ sumsq, int F){
  int f = threadIdx.x;
  float s = 0.f, s2 = 0.f;
  for (int i = blockIdx.x; i < N; i += gridDim.x){
    float v = y[i * F + f];
    s += v; s2 += v * v;
  }
  atomicAdd(&sums[f], s);
  atomicAdd(&sumsq[f], s2);
}

// BN-apply with inline param derivation; reads fp32, writes bf16. ACT: softplus.
template<int ACT>
__global__ void k_norm(const float* __restrict__ in, u16* __restrict__ outb,
                       const float* __restrict__ sums, const float* __restrict__ sumsq,
                       const float* __restrict__ gamma, const float* __restrict__ beta,
                       int n4, int fmask){
  int idx = blockIdx.x * 256 + threadIdx.x;
  if (idx >= n4) return;
  int base = idx << 2;
  int f = base & fmask;
  float4 s = *(const float4*)(sums + f);
  float4 q = *(const float4*)(sumsq + f);
  float4 g = *(const float4*)(gamma + f);
  float4 bt = *(const float4*)(beta + f);
  float4 v = *(const float4*)(in + base);
  const float inv = 1.f / N;
  float m, var, a, c;
  m = s.x * inv; var = q.x * inv - m * m; a = g.x * rsqrtf(var + EPS); c = bt.x - m * a; v.x = a * v.x + c;
  m = s.y * inv; var = q.y * inv - m * m; a = g.y * rsqrtf(var + EPS); c = bt.y - m * a; v.y = a * v.y + c;
  m = s.z * inv; var = q.z * inv - m * m; a = g.z * rsqrtf(var + EPS); c = bt.z - m * a; v.z = a * v.z + c;
  m = s.w * inv; var = q.w * inv - m * m; a = g.w * rsqrtf(var + EPS); c = bt.w - m * a; v.w = a * v.w + c;
  if (ACT){ v.x = sp(v.x); v.y = sp(v.y); v.z = sp(v.z); v.w = sp(v.w); }
  ushort4 o; o.x = f2b(v.x); o.y = f2b(v.y); o.z = f2b(v.z); o.w = f2b(v.w);
  *(ushort4*)(outb + base) = o;
}

// segmented pool over bf16 features: grid (G, POOL_S); partial sums + atomics into hg
__global__ void k_pool_seg(const u16* __restrict__ xb, const int* __restrict__ batch,
                           float* __restrict__ hg){
  int g = blockIdx.x, sl = blockIdx.y;
  int f = threadIdx.x;
  int lo = 0, hi = N;
  while (lo < hi){ int m = (lo + hi) >> 1; if (batch[m] < g) lo = m + 1; else hi = m; }
  int start = lo;
  lo = 0; hi = N;
  while (lo < hi){ int m = (lo + hi) >> 1; if (batch[m] < g + 1) lo = m + 1; else hi = m; }
  int end = lo;
  int len = end - start;
  int a = start + (int)((long)len * sl / POOL_S);
  int b = start + (int)((long)len * (sl + 1) / POOL_S);
  if (a >= b) return;
  float s = 0.f;
  for (int i = a; i < b; ++i) s += b2f(xb[(size_t)i * H + f]);
  atomicAdd(&hg[g * H + f], s);
}

// hgW[g][c] = sum_k hg[g][k] * W1[256+k][c] + B1[c]  (folds concat-half of GEMM1 + bias)
__global__ void k_hgw(const float* __restrict__ hg, const float* __restrict__ W1,
                      const float* __restrict__ B1, float* __restrict__ hgW){
  int g = blockIdx.x, c = threadIdx.x;
  float acc = B1[c];
  for (int k = 0; k < H; ++k)
    acc += hg[g * H + k] * W1[(size_t)(H + k) * H + c];
  hgW[g * H + c] = acc;
}

// convert W1-top/W2/W3 to bf16, transposed to [NC, K] row-major
__global__ void k_wconv(const float* __restrict__ W1, const float* __restrict__ W2,
                        const float* __restrict__ W3, u16* __restrict__ Wt1,
                        u16* __restrict__ Wt2, u16* __restrict__ Wt3){
  int idx = blockIdx.x * 256 + threadIdx.x;
  if (idx < 65536){                     // Wt1 [256,256] <- W1[0:256,256]
    int c = idx >> 8, k = idx & 255;
    Wt1[idx] = f2b(W1[(size_t)k * 256 + c]);
  } else if (idx < 98304){              // Wt2 [128,256] <- W2[256,128]
    int j = idx - 65536;
    int c = j >> 8, k = j & 255;
    Wt2[j] = f2b(W2[(size_t)k * 128 + c]);
  } else if (idx < 114688){             // Wt3 [128,128] <- W3[128,128]
    int j = idx - 98304;
    int c = j >> 7, k = j & 127;
    Wt3[j] = f2b(W3[(size_t)k * 128 + c]);
  }
}

// MFMA GEMM, 64x64 per wave: out[N,NC] = A[N,K](bf16) @ Wt[NC,K]^T(bf16) + epilogue.
// MODE 0: += hgW[batch[row]] -> fp32 out; MODE 1: += bias -> fp32 out;
// MODE 2: += bias -> split fp32 store to d_out.
template<int K, int NC, int MODE, int WR>
__global__ void k_mgemm(const u16* __restrict__ Ab, const u16* __restrict__ Wt,
                        const float* __restrict__ epi, const int* __restrict__ batch,
                        float* __restrict__ out){
  constexpr int WC = 4 / WR;
  int tid = threadIdx.x;
  int w = tid >> 6, lane = tid & 63;
  int quad = lane >> 4, l15 = lane & 15;
  int wr = w / WC, wc = w % WC;
  int rowBase = blockIdx.x * (WR * 64) + wr * 64;
  int colBase = wc * 64;
  const u16* arow[4];
  #pragma unroll
  for (int t = 0; t < 4; ++t){
    int am = rowBase + t * 16 + l15;
    if (am >= N) am = N - 1;            // clamp; stores are guarded
    arow[t] = Ab + (size_t)am * K + quad * 8;
  }
  const u16* brow[4];
  #pragma unroll
  for (int u = 0; u < 4; ++u)
    brow[u] = Wt + (size_t)(colBase + u * 16 + l15) * K + quad * 8;
  f32x4 acc[4][4] = {};
  for (int k0 = 0; k0 < K; k0 += 32){
    bf16x8 a[4], b[4];
    #pragma unroll
    for (int t = 0; t < 4; ++t) a[t] = *(const bf16x8*)(arow[t] + k0);
    #pragma unroll
    for (int u = 0; u < 4; ++u) b[u] = *(const bf16x8*)(brow[u] + k0);
    #pragma unroll
    for (int t = 0; t < 4; ++t)
      #pragma unroll
      for (int u = 0; u < 4; ++u)
        acc[t][u] = __builtin_amdgcn_mfma_f32_16x16x32_bf16(a[t], b[u], acc[t][u], 0, 0, 0);
  }
  #pragma unroll
  for (int t = 0; t < 4; ++t){
    #pragma unroll
    for (int r = 0; r < 4; ++r){
      int row = rowBase + t * 16 + quad * 4 + r;
      if (row >= N) continue;
      int g = (MODE == 0) ? batch[row] : 0;
      #pragma unroll
      for (int u = 0; u < 4; ++u){
        int n = colBase + u * 16 + l15;
        float v = acc[t][u][r];
        if (MODE == 0){
          v += epi[(size_t)g * NC + n];
          out[(size_t)row * NC + n] = v;
        } else if (MODE == 1){
          v += epi[n];
          out[(size_t)row * NC + n] = v;
        } else {
          v += epi[n];
          if (n < 64) out[(size_t)row * 64 + n] = v;
          else        out[(size_t)N * 64 + (size_t)row * 64 + (n - 64)] = v;
        }
      }
    }
  }
}

} // namespace

extern "C" void kernel_launch(void* const* d_in, const int* in_sizes, int n_in,
                              void* d_out, int out_size, void* d_ws, size_t ws_size,
                              hipStream_t stream){
  const int* node_type = (const int*)d_in[0];
  const int* edge_type = (const int*)d_in[1];
  const int* src       = (const int*)d_in[2];
  const int* dst       = src + E;
  const int* batch     = (const int*)d_in[3];
  const float* nemb = (const float*)d_in[4];
  const float* eemb = (const float*)d_in[5];
  const float* gs[3] = {(const float*)d_in[6], (const float*)d_in[8], (const float*)d_in[10]};
  const float* bs[3] = {(const float*)d_in[7], (const float*)d_in[9], (const float*)d_in[11]};
  const float* go1 = (const float*)d_in[12]; const float* bo1 = (const float*)d_in[13];
  const float* go2 = (const float*)d_in[14]; const float* bo2 = (const float*)d_in[15];
  const float* W1 = (const float*)d_in[16]; const float* B1 = (const float*)d_in[17];
  const float* W2 = (const float*)d_in[18]; const float* B2 = (const float*)d_in[19];
  const float* W3 = (const float*)d_in[20]; const float* B3 = (const float*)d_in[21];
  float* outf = (float*)d_out;

  float* ws   = (float*)d_ws;
  float* agg  = ws;                           // [N,256] fp32 (also GEMM1 out; GEMM2 out uses first N*128)
  float* hg   = agg + (size_t)N * H;          // [G,256]
  float* hgW  = hg  + (size_t)G * H;          // [G,256]
  float* stats = hgW + (size_t)G * H;         // sums|sumsq (512)
  float* sums = stats, *sumsq = stats + 256;
  int* cnt    = (int*)(stats + 512);          // [N]
  int* off    = cnt + N;                      // [N+1]
  int* cur    = off + N + 1;                  // [N]
  int* bsum   = cur + N;                      // [256]
  int* bbase  = bsum + 256;                   // [256]
  int2* edges_s = (int2*)(bbase + 256);       // [E]
  u16* xb     = (u16*)(edges_s + E);          // [N,256] bf16 features (x / Z1b / Z2b aliased)
  u16* Wt1    = xb + (size_t)N * H;           // [256,256] bf16
  u16* Wt2    = Wt1 + 65536;                  // [128,256]
  u16* Wt3    = Wt2 + 32768;                  // [128,128]
  float* xf   = (float*)(Wt3 + 16384 + 16);   // [N,128] fp32 (GEMM2 out)

  // ---- CSR build + weight conversion ----
  hipMemsetAsync(cnt, 0, (size_t)N * sizeof(int), stream);
  k_hist<<<(E + 255) / 256, 256, 0, stream>>>(dst, cnt);
  k_scan1<<<NB, 256, 0, stream>>>(cnt, bsum);
  k_scan2<<<1, 256, 0, stream>>>(bsum, bbase);
  k_scan3<<<NB, 256, 0, stream>>>(cnt, bbase, off, cur);
  k_fill<<<(E + 255) / 256, 256, 0, stream>>>(src, dst, edge_type, cur, edges_s);
  k_wconv<<<(114688 + 255) / 256, 256, 0, stream>>>(W1, W2, W3, Wt1, Wt2, Wt3);

  k_embed<<<(N * 64 + 255) / 256, 256, 0, stream>>>(node_type, nemb, xb);

  for (int l = 0; l < 3; ++l){
    k_gather<<<(N * 64 + 255) / 256, 256, 0, stream>>>(xb, agg, edges_s, off, eemb);
    hipMemsetAsync(sums, 0, 512 * sizeof(float), stream);
    k_stats<<<512, H, 0, stream>>>(agg, sums, sumsq, H);
    if (l < 2)
      k_norm<1><<<(N * 64 + 255) / 256, 256, 0, stream>>>(
          agg, xb, sums, sumsq, gs[l], bs[l], N * 64, 255);
    else
      k_norm<0><<<(N * 64 + 255) / 256, 256, 0, stream>>>(
          agg, xb, sums, sumsq, gs[l], bs[l], N * 64, 255);
  }

  hipMemsetAsync(hg, 0, (size_t)G * H * sizeof(float), stream);
  {
    dim3 pg(G, POOL_S);
    k_pool_seg<<<pg, H, 0, stream>>>(xb, batch, hg);
  }
  k_hgw<<<G, H, 0, stream>>>(hg, W1, B1, hgW);

  // GEMM1: xb @ W1top + hgW[batch] -> agg (fp32); 64x256 blocks
  k_mgemm<256, 256, 0, 1><<<(N + 63) / 64, 256, 0, stream>>>(xb, Wt1, hgW, batch, agg);
  hipMemsetAsync(sums, 0, 512 * sizeof(float), stream);
  k_stats<<<512, 256, 0, stream>>>(agg, sums, sumsq, 256);
  k_norm<1><<<(N * 64 + 255) / 256, 256, 0, stream>>>(
      agg, xb, sums, sumsq, go1, bo1, N * 64, 255);

  // GEMM2: Z1b @ W2 + B2 -> xf (fp32, [N,128]); 128x128 blocks
  k_mgemm<256, 128, 1, 2><<<(N + 127) / 128, 256, 0, stream>>>(xb, Wt2, B2, nullptr, xf);
  hipMemsetAsync(sums, 0, 512 * sizeof(float), stream);
  k_stats<<<512, 128, 0, stream>>>(xf, sums, sumsq, 128);
  k_norm<1><<<(N * 32 + 255) / 256, 256, 0, stream>>>(
      xf, xb, sums, sumsq, go2, bo2, N * 32, 127);

  // GEMM3: Z2b @ W3 + B3 -> split fp32 d_out; 128x128 blocks
  k_mgemm<128, 128, 2, 2><<<(N + 127) / 128, 256, 0, stream>>>(xb, Wt3, B3, nullptr, outf);
}

// Round 11
// 671.114 us; speedup vs baseline: 5.9345x; 1.0206x over previous
//
#include <hip/hip_runtime.h>
#include <hip/hip_bf16.h>

namespace {

constexpr int N = 50000;
constexpr int E = 300000;
constexpr int G = 256;
constexpr int H = 256;
constexpr float EPS = 1e-5f;
constexpr int NB = (N + 255) / 256;   // 196 scan blocks
constexpr int POOL_S = 8;             // row-slices per group in pool

typedef unsigned short u16;
typedef __attribute__((ext_vector_type(8))) short bf16x8;
typedef __attribute__((ext_vector_type(4))) float f32x4;

// fast softplus: max(z,0) + log(1+exp(-|z|)); exp arg in [-max,0] -> native safe
__device__ __forceinline__ float sp(float z){
  return fmaxf(z, 0.f) + __logf(1.f + __expf(-fabsf(z)));
}
// fp32 -> bf16 round-to-nearest-even
__device__ __forceinline__ u16 f2b(float f){
  union { float f; unsigned u; } v; v.f = f;
  unsigned r = v.u + 0x7FFF + ((v.u >> 16) & 1);
  return (u16)(r >> 16);
}
__device__ __forceinline__ float b2f(u16 u){
  union { unsigned i; float f; } v; v.i = ((unsigned)u) << 16; return v.f;
}
__device__ __forceinline__ float4 b2f4(ushort4 u){
  return make_float4(b2f(u.x), b2f(u.y), b2f(u.z), b2f(u.w));
}
__device__ __forceinline__ ushort4 f2b4(float4 v){
  ushort4 o; o.x = f2b(v.x); o.y = f2b(v.y); o.z = f2b(v.z); o.w = f2b(v.w);
  return o;
}

// xb[i,f] = bf16(node_emb_w[node_type[i], f])
__global__ void k_embed(const int* __restrict__ nt, const float* __restrict__ emb,
                        u16* __restrict__ xb){
  int idx = blockIdx.x * 256 + threadIdx.x;
  if (idx >= N * 64) return;
  int i = idx >> 6, fq = (idx & 63) << 2;
  float4 v = *(const float4*)(emb + (size_t)nt[i] * H + fq);
  *(ushort4*)(xb + (size_t)i * H + fq) = f2b4(v);
}

// ---- CSR build (by dst) ----
__global__ void k_hist(const int* __restrict__ dst, int* __restrict__ cnt){
  int e = blockIdx.x * 256 + threadIdx.x;
  if (e < E) atomicAdd(&cnt[dst[e]], 1);
}

__global__ void k_scan1(const int* __restrict__ cnt, int* __restrict__ bsum){
  __shared__ int s[256];
  int t = threadIdx.x;
  int i = blockIdx.x * 256 + t;
  s[t] = (i < N) ? cnt[i] : 0;
  __syncthreads();
  for (int d = 128; d > 0; d >>= 1){
    if (t < d) s[t] += s[t + d];
    __syncthreads();
  }
  if (t == 0) bsum[blockIdx.x] = s[0];
}

__global__ void k_scan2(const int* __restrict__ bsum, int* __restrict__ bbase){
  __shared__ int s[256];
  int t = threadIdx.x;
  int orig = (t < NB) ? bsum[t] : 0;
  s[t] = orig;
  __syncthreads();
  for (int d = 1; d < 256; d <<= 1){
    int v = (t >= d) ? s[t - d] : 0;
    __syncthreads();
    s[t] += v;
    __syncthreads();
  }
  bbase[t] = s[t] - orig;   // exclusive
}

__global__ void k_scan3(const int* __restrict__ cnt, const int* __restrict__ bbase,
                        int* __restrict__ off, int* __restrict__ cur){
  __shared__ int s[256];
  int t = threadIdx.x;
  int i = blockIdx.x * 256 + t;
  int v = (i < N) ? cnt[i] : 0;
  s[t] = v;
  __syncthreads();
  for (int d = 1; d < 256; d <<= 1){
    int u = (t >= d) ? s[t - d] : 0;
    __syncthreads();
    s[t] += u;
    __syncthreads();
  }
  int excl = bbase[blockIdx.x] + s[t] - v;
  if (i < N){ off[i] = excl; cur[i] = excl; }
  if (i == N - 1) off[N] = excl + v;   // == E
}

// edges_s[p] = (src*512, et*512) sorted by dst (byte offsets of bf16 rows)
__global__ void k_fill(const int* __restrict__ src, const int* __restrict__ dst,
                       const int* __restrict__ et, int* __restrict__ cur,
                       int2* __restrict__ edges_s){
  int e = blockIdx.x * 256 + threadIdx.x;
  if (e >= E) return;
  int d = dst[e];
  int p = atomicAdd(&cur[d], 1);
  edges_s[p] = make_int2(src[e] << 9, et[e] << 9);
}

__device__ __forceinline__ void acc_sp(float4& acc, const float4 xv, const float4 ev){
  acc.x += sp(xv.x + ev.x);
  acc.y += sp(xv.y + ev.y);
  acc.z += sp(xv.z + ev.z);
  acc.w += sp(xv.w + ev.w);
}

// agg[i] = xb[i] + sum_{e: dst=i} softplus(xb[src_e] + eembB[et_e]); one wave/node.
// 4-unroll main + 2 + 1 remainder cascade. All bf16 in, bf16 out.
__global__ void k_gather(const u16* __restrict__ xb, u16* __restrict__ agg,
                         const int2* __restrict__ edges_s, const int* __restrict__ off,
                         const u16* __restrict__ eembB){
  int gt = blockIdx.x * 256 + threadIdx.x;
  int i = gt >> 6;
  if (i >= N) return;
  int fqb = (gt & 63) << 3;                      // byte offset in row (4 bf16 = 8B)
  const char* xB = (const char*)xb;
  const char* eB = (const char*)eembB;
  float4 acc = b2f4(*(const ushort4*)(xB + ((size_t)i << 9) + fqb));
  int lo = off[i], hi = off[i + 1];
  int j = lo;
  for (; j + 4 <= hi; j += 4){
    int2 s0 = edges_s[j + 0];
    int2 s1 = edges_s[j + 1];
    int2 s2 = edges_s[j + 2];
    int2 s3 = edges_s[j + 3];
    ushort4 x0 = *(const ushort4*)(xB + s0.x + fqb);
    ushort4 x1 = *(const ushort4*)(xB + s1.x + fqb);
    ushort4 x2 = *(const ushort4*)(xB + s2.x + fqb);
    ushort4 x3 = *(const ushort4*)(xB + s3.x + fqb);
    ushort4 e0 = *(const ushort4*)(eB + s0.y + fqb);
    ushort4 e1 = *(const ushort4*)(eB + s1.y + fqb);
    ushort4 e2 = *(const ushort4*)(eB + s2.y + fqb);
    ushort4 e3 = *(const ushort4*)(eB + s3.y + fqb);
    acc_sp(acc, b2f4(x0), b2f4(e0));
    acc_sp(acc, b2f4(x1), b2f4(e1));
    acc_sp(acc, b2f4(x2), b2f4(e2));
    acc_sp(acc, b2f4(x3), b2f4(e3));
  }
  if (j + 2 <= hi){
    int2 s0 = edges_s[j + 0];
    int2 s1 = edges_s[j + 1];
    ushort4 x0 = *(const ushort4*)(xB + s0.x + fqb);
    ushort4 x1 = *(const ushort4*)(xB + s1.x + fqb);
    ushort4 e0 = *(const ushort4*)(eB + s0.y + fqb);
    ushort4 e1 = *(const ushort4*)(eB + s1.y + fqb);
    acc_sp(acc, b2f4(x0), b2f4(e0));
    acc_sp(acc, b2f4(x1), b2f4(e1));
    j += 2;
  }
  if (j < hi){
    int2 s0 = edges_s[j];
    ushort4 x0 = *(const ushort4*)(xB + s0.x + fqb);
    ushort4 e0 = *(const ushort4*)(eB + s0.y + fqb);
    acc_sp(acc, b2f4(x0), b2f4(e0));
  }
  *(ushort4*)((char*)agg + ((size_t)i << 9) + fqb) = f2b4(acc);
}

// per-feature sum / sumsq over N rows of bf16 y; blockDim.x == F
__global__ void k_stats(const u16* __restrict__ y, float* __restrict__ sums,
                        float* __restrict__ sumsq, int F){
  int f = threadIdx.x;
  float s = 0.f, s2 = 0.f;
  for (int i = blockIdx.x; i < N; i += gridDim.x){
    float v = b2f(y[(size_t)i * F + f]);
    s += v; s2 += v * v;
  }
  atomicAdd(&sums[f], s);
  atomicAdd(&sumsq[f], s2);
}

// BN-apply with inline param derivation; bf16 in, bf16 out. ACT: softplus.
template<int ACT>
__global__ void k_norm(const u16* __restrict__ in, u16* __restrict__ outb,
                       const float* __restrict__ sums, const float* __restrict__ sumsq,
                       const float* __restrict__ gamma, const float* __restrict__ beta,
                       int n4, int fmask){
  int idx = blockIdx.x * 256 + threadIdx.x;
  if (idx >= n4) return;
  int base = idx << 2;
  int f = base & fmask;
  float4 s = *(const float4*)(sums + f);
  float4 q = *(const float4*)(sumsq + f);
  float4 g = *(const float4*)(gamma + f);
  float4 bt = *(const float4*)(beta + f);
  float4 v = b2f4(*(const ushort4*)(in + base));
  const float inv = 1.f / N;
  float m, var, a, c;
  m = s.x * inv; var = q.x * inv - m * m; a = g.x * rsqrtf(var + EPS); c = bt.x - m * a; v.x = a * v.x + c;
  m = s.y * inv; var = q.y * inv - m * m; a = g.y * rsqrtf(var + EPS); c = bt.y - m * a; v.y = a * v.y + c;
  m = s.z * inv; var = q.z * inv - m * m; a = g.z * rsqrtf(var + EPS); c = bt.z - m * a; v.z = a * v.z + c;
  m = s.w * inv; var = q.w * inv - m * m; a = g.w * rsqrtf(var + EPS); c = bt.w - m * a; v.w = a * v.w + c;
  if (ACT){ v.x = sp(v.x); v.y = sp(v.y); v.z = sp(v.z); v.w = sp(v.w); }
  *(ushort4*)(outb + base) = f2b4(v);
}

// segmented pool over bf16 features: grid (G, POOL_S); partial sums + atomics into hg
__global__ void k_pool_seg(const u16* __restrict__ xb, const int* __restrict__ batch,
                           float* __restrict__ hg){
  int g = blockIdx.x, sl = blockIdx.y;
  int f = threadIdx.x;
  int lo = 0, hi = N;
  while (lo < hi){ int m = (lo + hi) >> 1; if (batch[m] < g) lo = m + 1; else hi = m; }
  int start = lo;
  lo = 0; hi = N;
  while (lo < hi){ int m = (lo + hi) >> 1; if (batch[m] < g + 1) lo = m + 1; else hi = m; }
  int end = lo;
  int len = end - start;
  int a = start + (int)((long)len * sl / POOL_S);
  int b = start + (int)((long)len * (sl + 1) / POOL_S);
  if (a >= b) return;
  float s = 0.f;
  for (int i = a; i < b; ++i) s += b2f(xb[(size_t)i * H + f]);
  atomicAdd(&hg[g * H + f], s);
}

// hgW[g][c] = sum_k hg[g][k] * W1[256+k][c] + B1[c]  (folds concat-half of GEMM1 + bias)
__global__ void k_hgw(const float* __restrict__ hg, const float* __restrict__ W1,
                      const float* __restrict__ B1, float* __restrict__ hgW){
  int g = blockIdx.x, c = threadIdx.x;
  float acc = B1[c];
  for (int k = 0; k < H; ++k)
    acc += hg[g * H + k] * W1[(size_t)(H + k) * H + c];
  hgW[g * H + c] = acc;
}

// convert W1-top/W2/W3 to bf16 [NC,K] row-major + eemb to bf16
__global__ void k_wconv(const float* __restrict__ W1, const float* __restrict__ W2,
                        const float* __restrict__ W3, const float* __restrict__ eemb,
                        u16* __restrict__ Wt1, u16* __restrict__ Wt2,
                        u16* __restrict__ Wt3, u16* __restrict__ eembB){
  int idx = blockIdx.x * 256 + threadIdx.x;
  if (idx < 65536){                     // Wt1 [256,256] <- W1[0:256,256]
    int c = idx >> 8, k = idx & 255;
    Wt1[idx] = f2b(W1[(size_t)k * 256 + c]);
  } else if (idx < 98304){              // Wt2 [128,256] <- W2[256,128]
    int j = idx - 65536;
    int c = j >> 8, k = j & 255;
    Wt2[j] = f2b(W2[(size_t)k * 128 + c]);
  } else if (idx < 114688){             // Wt3 [128,128] <- W3[128,128]
    int j = idx - 98304;
    int c = j >> 7, k = j & 127;
    Wt3[j] = f2b(W3[(size_t)k * 128 + c]);
  } else if (idx < 114688 + 25600){     // eembB [100,256]
    int j = idx - 114688;
    eembB[j] = f2b(eemb[j]);
  }
}

// MFMA GEMM, 64x64 per wave: A[N,K](bf16) @ Wt[NC,K]^T(bf16) + epilogue.
// MODE 0: += hgW[batch[row]] -> bf16 out; MODE 1: += bias -> bf16 out;
// MODE 2: += bias -> split fp32 store to d_out.
template<int K, int NC, int MODE, int WR>
__global__ void k_mgemm(const u16* __restrict__ Ab, const u16* __restrict__ Wt,
                        const float* __restrict__ epi, const int* __restrict__ batch,
                        u16* __restrict__ outb, float* __restrict__ outf){
  constexpr int WC = 4 / WR;
  int tid = threadIdx.x;
  int w = tid >> 6, lane = tid & 63;
  int quad = lane >> 4, l15 = lane & 15;
  int wr = w / WC, wc = w % WC;
  int rowBase = blockIdx.x * (WR * 64) + wr * 64;
  int colBase = wc * 64;
  const u16* arow[4];
  #pragma unroll
  for (int t = 0; t < 4; ++t){
    int am = rowBase + t * 16 + l15;
    if (am >= N) am = N - 1;            // clamp; stores are guarded
    arow[t] = Ab + (size_t)am * K + quad * 8;
  }
  const u16* brow[4];
  #pragma unroll
  for (int u = 0; u < 4; ++u)
    brow[u] = Wt + (size_t)(colBase + u * 16 + l15) * K + quad * 8;
  f32x4 acc[4][4] = {};
  for (int k0 = 0; k0 < K; k0 += 32){
    bf16x8 a[4], b[4];
    #pragma unroll
    for (int t = 0; t < 4; ++t) a[t] = *(const bf16x8*)(arow[t] + k0);
    #pragma unroll
    for (int u = 0; u < 4; ++u) b[u] = *(const bf16x8*)(brow[u] + k0);
    #pragma unroll
    for (int t = 0; t < 4; ++t)
      #pragma unroll
      for (int u = 0; u < 4; ++u)
        acc[t][u] = __builtin_amdgcn_mfma_f32_16x16x32_bf16(a[t], b[u], acc[t][u], 0, 0, 0);
  }
  #pragma unroll
  for (int t = 0; t < 4; ++t){
    #pragma unroll
    for (int r = 0; r < 4; ++r){
      int row = rowBase + t * 16 + quad * 4 + r;
      if (row >= N) continue;
      int g = (MODE == 0) ? batch[row] : 0;
      #pragma unroll
      for (int u = 0; u < 4; ++u){
        int n = colBase + u * 16 + l15;
        float v = acc[t][u][r];
        if (MODE == 0){
          v += epi[(size_t)g * NC + n];
          outb[(size_t)row * NC + n] = f2b(v);
        } else if (MODE == 1){
          v += epi[n];
          outb[(size_t)row * NC + n] = f2b(v);
        } else {
          v += epi[n];
          if (n < 64) outf[(size_t)row * 64 + n] = v;
          else        outf[(size_t)N * 64 + (size_t)row * 64 + (n - 64)] = v;
        }
      }
    }
  }
}

} // namespace

extern "C" void kernel_launch(void* const* d_in, const int* in_sizes, int n_in,
                              void* d_out, int out_size, void* d_ws, size_t ws_size,
                              hipStream_t stream){
  const int* node_type = (const int*)d_in[0];
  const int* edge_type = (const int*)d_in[1];
  const int* src       = (const int*)d_in[2];
  const int* dst       = src + E;
  const int* batch     = (const int*)d_in[3];
  const float* nemb = (const float*)d_in[4];
  const float* eemb = (const float*)d_in[5];
  const float* gs[3] = {(const float*)d_in[6], (const float*)d_in[8], (const float*)d_in[10]};
  const float* bs[3] = {(const float*)d_in[7], (const float*)d_in[9], (const float*)d_in[11]};
  const float* go1 = (const float*)d_in[12]; const float* bo1 = (const float*)d_in[13];
  const float* go2 = (const float*)d_in[14]; const float* bo2 = (const float*)d_in[15];
  const float* W1 = (const float*)d_in[16]; const float* B1 = (const float*)d_in[17];
  const float* W2 = (const float*)d_in[18]; const float* B2 = (const float*)d_in[19];
  const float* W3 = (const float*)d_in[20]; const float* B3 = (const float*)d_in[21];
  float* outf = (float*)d_out;

  // ---- workspace layout: [cnt | hg | statsAll] contiguous => single memset ----
  char* p = (char*)d_ws;
  int*   cnt    = (int*)p;              p += (size_t)N * 4;
  float* hg     = (float*)p;            p += (size_t)G * H * 4;
  float* statsA = (float*)p;            p += 5 * 512 * 4;   // 5 pairs of sums|sumsq
  size_t zeroBytes = (size_t)p - (size_t)d_ws;
  float* hgW    = (float*)p;            p += (size_t)G * H * 4;
  int*   off    = (int*)p;              p += (size_t)(N + 1) * 4;
  int*   cur    = (int*)p;              p += (size_t)N * 4;
  int*   bsum   = (int*)p;              p += 256 * 4;
  int*   bbase  = (int*)p;              p += 256 * 4;
  int2*  edges_s= (int2*)p;             p += (size_t)E * 8;
  u16*   xb     = (u16*)p;              p += (size_t)N * H * 2;
  u16*   agg    = (u16*)p;              p += (size_t)N * H * 2;
  u16*   xf     = (u16*)p;              p += (size_t)N * 128 * 2;
  u16*   Wt1    = (u16*)p;              p += 65536 * 2;
  u16*   Wt2    = (u16*)p;              p += 32768 * 2;
  u16*   Wt3    = (u16*)p;              p += 16384 * 2;
  u16*   eembB  = (u16*)p;              p += 25600 * 2;
  float* sumsL[5], *sumsqL[5];
  for (int k = 0; k < 5; ++k){ sumsL[k] = statsA + k * 512; sumsqL[k] = statsA + k * 512 + 256; }

  hipMemsetAsync(d_ws, 0, zeroBytes, stream);   // cnt + hg + all stats

  // ---- CSR build + weight/eemb conversion ----
  k_hist<<<(E + 255) / 256, 256, 0, stream>>>(dst, cnt);
  k_scan1<<<NB, 256, 0, stream>>>(cnt, bsum);
  k_scan2<<<1, 256, 0, stream>>>(bsum, bbase);
  k_scan3<<<NB, 256, 0, stream>>>(cnt, bbase, off, cur);
  k_fill<<<(E + 255) / 256, 256, 0, stream>>>(src, dst, edge_type, cur, edges_s);
  k_wconv<<<(140288 + 255) / 256, 256, 0, stream>>>(W1, W2, W3, eemb, Wt1, Wt2, Wt3, eembB);

  k_embed<<<(N * 64 + 255) / 256, 256, 0, stream>>>(node_type, nemb, xb);

  for (int l = 0; l < 3; ++l){
    k_gather<<<(N * 64 + 255) / 256, 256, 0, stream>>>(xb, agg, edges_s, off, eembB);
    k_stats<<<512, H, 0, stream>>>(agg, sumsL[l], sumsqL[l], H);
    if (l < 2)
      k_norm<1><<<(N * 64 + 255) / 256, 256, 0, stream>>>(
          agg, xb, sumsL[l], sumsqL[l], gs[l], bs[l], N * 64, 255);
    else
      k_norm<0><<<(N * 64 + 255) / 256, 256, 0, stream>>>(
          agg, xb, sumsL[l], sumsqL[l], gs[l], bs[l], N * 64, 255);
  }

  {
    dim3 pg(G, POOL_S);
    k_pool_seg<<<pg, H, 0, stream>>>(xb, batch, hg);
  }
  k_hgw<<<G, H, 0, stream>>>(hg, W1, B1, hgW);

  // GEMM1: xb @ W1top + hgW[batch] -> agg (bf16); 64x256 blocks
  k_mgemm<256, 256, 0, 1><<<(N + 63) / 64, 256, 0, stream>>>(xb, Wt1, hgW, batch, agg, nullptr);
  k_stats<<<512, 256, 0, stream>>>(agg, sumsL[3], sumsqL[3], 256);
  k_norm<1><<<(N * 64 + 255) / 256, 256, 0, stream>>>(
      agg, xb, sumsL[3], sumsqL[3], go1, bo1, N * 64, 255);

  // GEMM2: Z1b @ W2 + B2 -> xf (bf16, [N,128]); 128x128 blocks
  k_mgemm<256, 128, 1, 2><<<(N + 127) / 128, 256, 0, stream>>>(xb, Wt2, B2, nullptr, xf, nullptr);
  k_stats<<<512, 128, 0, stream>>>(xf, sumsL[4], sumsqL[4], 128);
  k_norm<1><<<(N * 32 + 255) / 256, 256, 0, stream>>>(
      xf, xb, sumsL[4], sumsqL[4], go2, bo2, N * 32, 127);

  // GEMM3: Z2b @ W3 + B3 -> split fp32 d_out; 128x128 blocks
  k_mgemm<128, 128, 2, 2><<<(N + 127) / 128, 256, 0, stream>>>(xb, Wt3, B3, nullptr, nullptr, outf);
}

// Round 12
// 620.984 us; speedup vs baseline: 6.4136x; 1.0807x over previous
//
#include <hip/hip_runtime.h>
#include <hip/hip_bf16.h>

namespace {

constexpr int N = 50000;
constexpr int E = 300000;
constexpr int G = 256;
constexpr int H = 256;
constexpr float EPS = 1e-5f;
constexpr int NB = (N + 255) / 256;   // 196 scan blocks
constexpr int POOL_S = 16;            // row-slices per group in pool
constexpr float LOG2E = 1.4426950408889634f;
constexpr float LN2   = 0.6931471805599453f;

typedef unsigned short u16;
typedef __attribute__((ext_vector_type(8))) short bf16x8;
typedef __attribute__((ext_vector_type(4))) float f32x4;

// native transcendentals; v_exp_f32 = 2^x, v_log_f32 = log2(x); -abs() is a free modifier
__device__ __forceinline__ float expnabs(float z){
  float r; asm("v_exp_f32 %0, -abs(%1)" : "=v"(r) : "v"(z)); return r;
}
__device__ __forceinline__ float log2f_(float x){
  float r; asm("v_log_f32 %0, %1" : "=v"(r) : "v"(x)); return r;
}
// scaled softplus: input z' = z*log2e; returns log2e*softplus(z) -- zero multiplies
__device__ __forceinline__ float spw(float zs){
  return fmaxf(zs, 0.f) + log2f_(1.f + expnabs(zs));
}
// fp32 -> bf16 RNE
__device__ __forceinline__ u16 f2b(float f){
  union { float f; unsigned u; } v; v.f = f;
  unsigned r = v.u + 0x7FFF + ((v.u >> 16) & 1);
  return (u16)(r >> 16);
}
__device__ __forceinline__ float b2f(u16 u){
  union { unsigned i; float f; } v; v.i = ((unsigned)u) << 16; return v.f;
}
__device__ __forceinline__ float4 b2f4(ushort4 u){
  return make_float4(b2f(u.x), b2f(u.y), b2f(u.z), b2f(u.w));
}
__device__ __forceinline__ ushort4 f2b4(float4 v){
  ushort4 o; o.x = f2b(v.x); o.y = f2b(v.y); o.z = f2b(v.z); o.w = f2b(v.w);
  return o;
}

// merged prologue: embed (scaled bf16) | edge histogram | weight conversion | eemb*log2e
__global__ void k_pre(const int* __restrict__ nt, const float* __restrict__ nemb,
                      u16* __restrict__ xb, const int* __restrict__ dst,
                      int* __restrict__ cnt,
                      const float* __restrict__ W1, const float* __restrict__ W2,
                      const float* __restrict__ W3, const float* __restrict__ eemb,
                      u16* __restrict__ Wt1, u16* __restrict__ Wt2,
                      u16* __restrict__ Wt3, float* __restrict__ eembF){
  int idx = blockIdx.x * 256 + threadIdx.x;
  if (idx < N * 64){
    int i = idx >> 6, fq = (idx & 63) << 2;
    float4 v = *(const float4*)(nemb + (size_t)nt[i] * H + fq);
    v.x *= LOG2E; v.y *= LOG2E; v.z *= LOG2E; v.w *= LOG2E;
    *(ushort4*)(xb + (size_t)i * H + fq) = f2b4(v);
    return;
  }
  int j = idx - N * 64;
  if (j < E){ atomicAdd(&cnt[dst[j]], 1); return; }
  j -= E;
  if (j < 65536){                       // Wt1 [256,256] <- W1[0:256,256]
    int c = j >> 8, k = j & 255;
    Wt1[j] = f2b(W1[(size_t)k * 256 + c]);
    return;
  }
  j -= 65536;
  if (j < 32768){                       // Wt2 [128,256] <- W2[256,128]
    int c = j >> 8, k = j & 255;
    Wt2[j] = f2b(W2[(size_t)k * 128 + c]);
    return;
  }
  j -= 32768;
  if (j < 16384){                       // Wt3 [128,128] <- W3[128,128]
    int c = j >> 7, k = j & 127;
    Wt3[j] = f2b(W3[(size_t)k * 128 + c]);
    return;
  }
  j -= 16384;
  if (j < 25600) eembF[j] = eemb[j] * LOG2E;
}

// ---- CSR scan ----
__global__ void k_scan1(const int* __restrict__ cnt, int* __restrict__ bsum){
  __shared__ int s[256];
  int t = threadIdx.x;
  int i = blockIdx.x * 256 + t;
  s[t] = (i < N) ? cnt[i] : 0;
  __syncthreads();
  for (int d = 128; d > 0; d >>= 1){
    if (t < d) s[t] += s[t + d];
    __syncthreads();
  }
  if (t == 0) bsum[blockIdx.x] = s[0];
}

__global__ void k_scan2(const int* __restrict__ bsum, int* __restrict__ bbase){
  __shared__ int s[256];
  int t = threadIdx.x;
  int orig = (t < NB) ? bsum[t] : 0;
  s[t] = orig;
  __syncthreads();
  for (int d = 1; d < 256; d <<= 1){
    int v = (t >= d) ? s[t - d] : 0;
    __syncthreads();
    s[t] += v;
    __syncthreads();
  }
  bbase[t] = s[t] - orig;   // exclusive
}

__global__ void k_scan3(const int* __restrict__ cnt, const int* __restrict__ bbase,
                        int* __restrict__ off, int* __restrict__ cur){
  __shared__ int s[256];
  int t = threadIdx.x;
  int i = blockIdx.x * 256 + t;
  int v = (i < N) ? cnt[i] : 0;
  s[t] = v;
  __syncthreads();
  for (int d = 1; d < 256; d <<= 1){
    int u = (t >= d) ? s[t - d] : 0;
    __syncthreads();
    s[t] += u;
    __syncthreads();
  }
  int excl = bbase[blockIdx.x] + s[t] - v;
  if (i < N){ off[i] = excl; cur[i] = excl; }
  if (i == N - 1) off[N] = excl + v;   // == E
}

// edges_s[p] = (src*512, et*1024): byte offsets into bf16 xb rows / fp32 eembF rows
__global__ void k_fill(const int* __restrict__ src, const int* __restrict__ dst,
                       const int* __restrict__ et, int* __restrict__ cur,
                       int2* __restrict__ edges_s){
  int e = blockIdx.x * 256 + threadIdx.x;
  if (e >= E) return;
  int d = dst[e];
  int p = atomicAdd(&cur[d], 1);
  edges_s[p] = make_int2(src[e] << 9, et[e] << 10);
}

__device__ __forceinline__ void acc_w(float4& acc, const float4 xs, const float4 es){
  acc.x += spw(xs.x + es.x);
  acc.y += spw(xs.y + es.y);
  acc.z += spw(xs.z + es.z);
  acc.w += spw(xs.w + es.w);
}

// agg_true[i] = ln2 * ( xb_scaled[i] + sum_e spw(xb_scaled[src]+eembF_scaled[et]) )
__global__ void k_gather(const u16* __restrict__ xb, u16* __restrict__ agg,
                         const int2* __restrict__ edges_s, const int* __restrict__ off,
                         const float* __restrict__ eembF){
  int gt = blockIdx.x * 256 + threadIdx.x;
  int i = gt >> 6;
  if (i >= N) return;
  int fx = (gt & 63) << 3;                       // byte offset in bf16 row
  int fe = (gt & 63) << 4;                       // byte offset in fp32 row
  const char* xB = (const char*)xb;
  const char* eB = (const char*)eembF;
  float4 acc = b2f4(*(const ushort4*)(xB + ((size_t)i << 9) + fx));  // scaled
  int lo = off[i], hi = off[i + 1];
  int j = lo;
  for (; j + 4 <= hi; j += 4){
    int2 s0 = edges_s[j + 0];
    int2 s1 = edges_s[j + 1];
    int2 s2 = edges_s[j + 2];
    int2 s3 = edges_s[j + 3];
    ushort4 x0 = *(const ushort4*)(xB + s0.x + fx);
    ushort4 x1 = *(const ushort4*)(xB + s1.x + fx);
    ushort4 x2 = *(const ushort4*)(xB + s2.x + fx);
    ushort4 x3 = *(const ushort4*)(xB + s3.x + fx);
    float4 e0 = *(const float4*)(eB + s0.y + fe);
    float4 e1 = *(const float4*)(eB + s1.y + fe);
    float4 e2 = *(const float4*)(eB + s2.y + fe);
    float4 e3 = *(const float4*)(eB + s3.y + fe);
    acc_w(acc, b2f4(x0), e0);
    acc_w(acc, b2f4(x1), e1);
    acc_w(acc, b2f4(x2), e2);
    acc_w(acc, b2f4(x3), e3);
  }
  if (j + 2 <= hi){
    int2 s0 = edges_s[j + 0];
    int2 s1 = edges_s[j + 1];
    ushort4 x0 = *(const ushort4*)(xB + s0.x + fx);
    ushort4 x1 = *(const ushort4*)(xB + s1.x + fx);
    float4 e0 = *(const float4*)(eB + s0.y + fe);
    float4 e1 = *(const float4*)(eB + s1.y + fe);
    acc_w(acc, b2f4(x0), e0);
    acc_w(acc, b2f4(x1), e1);
    j += 2;
  }
  if (j < hi){
    int2 s0 = edges_s[j];
    ushort4 x0 = *(const ushort4*)(xB + s0.x + fx);
    float4 e0 = *(const float4*)(eB + s0.y + fe);
    acc_w(acc, b2f4(x0), e0);
  }
  acc.x *= LN2; acc.y *= LN2; acc.z *= LN2; acc.w *= LN2;   // back to true scale
  *(ushort4*)((char*)agg + ((size_t)i << 9) + fx) = f2b4(acc);
}

// per-feature sum / sumsq over N rows of bf16 y; blockDim.x == F
__global__ void k_stats(const u16* __restrict__ y, float* __restrict__ sums,
                        float* __restrict__ sumsq, int F){
  int f = threadIdx.x;
  float s = 0.f, s2 = 0.f;
  for (int i = blockIdx.x; i < N; i += gridDim.x){
    float v = b2f(y[(size_t)i * F + f]);
    s += v; s2 += v * v;
  }
  atomicAdd(&sums[f], s);
  atomicAdd(&sumsq[f], s2);
}

// BN-apply, bf16 in -> bf16 out. ACT: softplus. SCALED: output *log2e (for gather input).
template<int ACT, int SCALED>
__global__ void k_norm(const u16* __restrict__ in, u16* __restrict__ outb,
                       const float* __restrict__ sums, const float* __restrict__ sumsq,
                       const float* __restrict__ gamma, const float* __restrict__ beta,
                       int n4, int fmask){
  int idx = blockIdx.x * 256 + threadIdx.x;
  if (idx >= n4) return;
  int base = idx << 2;
  int f = base & fmask;
  float4 s = *(const float4*)(sums + f);
  float4 q = *(const float4*)(sumsq + f);
  float4 g = *(const float4*)(gamma + f);
  float4 bt = *(const float4*)(beta + f);
  float4 v = b2f4(*(const ushort4*)(in + base));
  const float inv = 1.f / N;
  float m, var, a, c;
  m = s.x * inv; var = q.x * inv - m * m; a = g.x * rsqrtf(var + EPS); c = bt.x - m * a; v.x = a * v.x + c;
  m = s.y * inv; var = q.y * inv - m * m; a = g.y * rsqrtf(var + EPS); c = bt.y - m * a; v.y = a * v.y + c;
  m = s.z * inv; var = q.z * inv - m * m; a = g.z * rsqrtf(var + EPS); c = bt.z - m * a; v.z = a * v.z + c;
  m = s.w * inv; var = q.w * inv - m * m; a = g.w * rsqrtf(var + EPS); c = bt.w - m * a; v.w = a * v.w + c;
  if (ACT){
    v.x = spw(v.x * LOG2E); v.y = spw(v.y * LOG2E);
    v.z = spw(v.z * LOG2E); v.w = spw(v.w * LOG2E);
    if (!SCALED){ v.x *= LN2; v.y *= LN2; v.z *= LN2; v.w *= LN2; }
  }
  *(ushort4*)(outb + base) = f2b4(v);
}

// segmented pool over (unscaled) bf16 features: grid (G, POOL_S)
__global__ void k_pool_seg(const u16* __restrict__ xb, const int* __restrict__ batch,
                           float* __restrict__ hg){
  int g = blockIdx.x, sl = blockIdx.y;
  int f = threadIdx.x;
  int lo = 0, hi = N;
  while (lo < hi){ int m = (lo + hi) >> 1; if (batch[m] < g) lo = m + 1; else hi = m; }
  int start = lo;
  lo = 0; hi = N;
  while (lo < hi){ int m = (lo + hi) >> 1; if (batch[m] < g + 1) lo = m + 1; else hi = m; }
  int end = lo;
  int len = end - start;
  int a = start + (int)((long)len * sl / POOL_S);
  int b = start + (int)((long)len * (sl + 1) / POOL_S);
  if (a >= b) return;
  float s = 0.f;
  for (int i = a; i < b; ++i) s += b2f(xb[(size_t)i * H + f]);
  atomicAdd(&hg[g * H + f], s);
}

// hgW[g][c] = sum_k hg[g][k] * W1[256+k][c] + B1[c]
__global__ void k_hgw(const float* __restrict__ hg, const float* __restrict__ W1,
                      const float* __restrict__ B1, float* __restrict__ hgW){
  int g = blockIdx.x, c = threadIdx.x;
  float acc = B1[c];
  for (int k = 0; k < H; ++k)
    acc += hg[g * H + k] * W1[(size_t)(H + k) * H + c];
  hgW[g * H + c] = acc;
}

// MFMA GEMM, 64x64 per wave: A[N,K](bf16) @ Wt[NC,K]^T(bf16) + epilogue.
// MODE 0: += hgW[batch[row]] -> bf16 out; MODE 1: += bias -> bf16 out;
// MODE 2: += bias -> split fp32 store to d_out.
template<int K, int NC, int MODE, int WR>
__global__ void k_mgemm(const u16* __restrict__ Ab, const u16* __restrict__ Wt,
                        const float* __restrict__ epi, const int* __restrict__ batch,
                        u16* __restrict__ outb, float* __restrict__ outf){
  constexpr int WC = 4 / WR;
  int tid = threadIdx.x;
  int w = tid >> 6, lane = tid & 63;
  int quad = lane >> 4, l15 = lane & 15;
  int wr = w / WC, wc = w % WC;
  int rowBase = blockIdx.x * (WR * 64) + wr * 64;
  int colBase = wc * 64;
  const u16* arow[4];
  #pragma unroll
  for (int t = 0; t < 4; ++t){
    int am = rowBase + t * 16 + l15;
    if (am >= N) am = N - 1;            // clamp; stores are guarded
    arow[t] = Ab + (size_t)am * K + quad * 8;
  }
  const u16* brow[4];
  #pragma unroll
  for (int u = 0; u < 4; ++u)
    brow[u] = Wt + (size_t)(colBase + u * 16 + l15) * K + quad * 8;
  f32x4 acc[4][4] = {};
  for (int k0 = 0; k0 < K; k0 += 32){
    bf16x8 a[4], b[4];
    #pragma unroll
    for (int t = 0; t < 4; ++t) a[t] = *(const bf16x8*)(arow[t] + k0);
    #pragma unroll
    for (int u = 0; u < 4; ++u) b[u] = *(const bf16x8*)(brow[u] + k0);
    #pragma unroll
    for (int t = 0; t < 4; ++t)
      #pragma unroll
      for (int u = 0; u < 4; ++u)
        acc[t][u] = __builtin_amdgcn_mfma_f32_16x16x32_bf16(a[t], b[u], acc[t][u], 0, 0, 0);
  }
  #pragma unroll
  for (int t = 0; t < 4; ++t){
    #pragma unroll
    for (int r = 0; r < 4; ++r){
      int row = rowBase + t * 16 + quad * 4 + r;
      if (row >= N) continue;
      int g = (MODE == 0) ? batch[row] : 0;
      #pragma unroll
      for (int u = 0; u < 4; ++u){
        int n = colBase + u * 16 + l15;
        float v = acc[t][u][r];
        if (MODE == 0){
          v += epi[(size_t)g * NC + n];
          outb[(size_t)row * NC + n] = f2b(v);
        } else if (MODE == 1){
          v += epi[n];
          outb[(size_t)row * NC + n] = f2b(v);
        } else {
          v += epi[n];
          if (n < 64) outf[(size_t)row * 64 + n] = v;
          else        outf[(size_t)N * 64 + (size_t)row * 64 + (n - 64)] = v;
        }
      }
    }
  }
}

} // namespace

extern "C" void kernel_launch(void* const* d_in, const int* in_sizes, int n_in,
                              void* d_out, int out_size, void* d_ws, size_t ws_size,
                              hipStream_t stream){
  const int* node_type = (const int*)d_in[0];
  const int* edge_type = (const int*)d_in[1];
  const int* src       = (const int*)d_in[2];
  const int* dst       = src + E;
  const int* batch     = (const int*)d_in[3];
  const float* nemb = (const float*)d_in[4];
  const float* eemb = (const float*)d_in[5];
  const float* gs[3] = {(const float*)d_in[6], (const float*)d_in[8], (const float*)d_in[10]};
  const float* bs[3] = {(const float*)d_in[7], (const float*)d_in[9], (const float*)d_in[11]};
  const float* go1 = (const float*)d_in[12]; const float* bo1 = (const float*)d_in[13];
  const float* go2 = (const float*)d_in[14]; const float* bo2 = (const float*)d_in[15];
  const float* W1 = (const float*)d_in[16]; const float* B1 = (const float*)d_in[17];
  const float* W2 = (const float*)d_in[18]; const float* B2 = (const float*)d_in[19];
  const float* W3 = (const float*)d_in[20]; const float* B3 = (const float*)d_in[21];
  float* outf = (float*)d_out;

  // ---- workspace layout: [cnt | hg | statsAll] contiguous => single memset ----
  char* p = (char*)d_ws;
  int*   cnt    = (int*)p;              p += (size_t)N * 4;
  float* hg     = (float*)p;            p += (size_t)G * H * 4;
  float* statsA = (float*)p;            p += 5 * 512 * 4;   // 5 pairs of sums|sumsq
  size_t zeroBytes = (size_t)p - (size_t)d_ws;
  float* hgW    = (float*)p;            p += (size_t)G * H * 4;
  int*   off    = (int*)p;              p += (size_t)(N + 1) * 4;
  int*   cur    = (int*)p;              p += (size_t)N * 4;
  int*   bsum   = (int*)p;              p += 256 * 4;
  int*   bbase  = (int*)p;              p += 256 * 4;
  int2*  edges_s= (int2*)p;             p += (size_t)E * 8;
  u16*   xb     = (u16*)p;              p += (size_t)N * H * 2;
  u16*   agg    = (u16*)p;              p += (size_t)N * H * 2;
  u16*   xf     = (u16*)p;              p += (size_t)N * 128 * 2;
  u16*   Wt1    = (u16*)p;              p += 65536 * 2;
  u16*   Wt2    = (u16*)p;              p += 32768 * 2;
  u16*   Wt3    = (u16*)p;              p += 16384 * 2;
  float* eembF  = (float*)p;            p += 25600 * 4;
  float* sumsL[5], *sumsqL[5];
  for (int k = 0; k < 5; ++k){ sumsL[k] = statsA + k * 512; sumsqL[k] = statsA + k * 512 + 256; }

  hipMemsetAsync(d_ws, 0, zeroBytes, stream);   // cnt + hg + all stats

  // ---- merged prologue (embed + hist + weight conv), then scan + fill ----
  const int preItems = N * 64 + E + 65536 + 32768 + 16384 + 25600;
  k_pre<<<(preItems + 255) / 256, 256, 0, stream>>>(
      node_type, nemb, xb, dst, cnt, W1, W2, W3, eemb, Wt1, Wt2, Wt3, eembF);
  k_scan1<<<NB, 256, 0, stream>>>(cnt, bsum);
  k_scan2<<<1, 256, 0, stream>>>(bsum, bbase);
  k_scan3<<<NB, 256, 0, stream>>>(cnt, bbase, off, cur);
  k_fill<<<(E + 255) / 256, 256, 0, stream>>>(src, dst, edge_type, cur, edges_s);

  for (int l = 0; l < 3; ++l){
    k_gather<<<(N * 64 + 255) / 256, 256, 0, stream>>>(xb, agg, edges_s, off, eembF);
    k_stats<<<1024, H, 0, stream>>>(agg, sumsL[l], sumsqL[l], H);
    if (l < 2)
      k_norm<1, 1><<<(N * 64 + 255) / 256, 256, 0, stream>>>(
          agg, xb, sumsL[l], sumsqL[l], gs[l], bs[l], N * 64, 255);
    else  // layer 3: unscaled (feeds pool + GEMM1)
      k_norm<0, 0><<<(N * 64 + 255) / 256, 256, 0, stream>>>(
          agg, xb, sumsL[l], sumsqL[l], gs[l], bs[l], N * 64, 255);
  }

  {
    dim3 pg(G, POOL_S);
    k_pool_seg<<<pg, H, 0, stream>>>(xb, batch, hg);
  }
  k_hgw<<<G, H, 0, stream>>>(hg, W1, B1, hgW);

  // GEMM1: xb @ W1top + hgW[batch] -> agg (bf16); 64x256 blocks
  k_mgemm<256, 256, 0, 1><<<(N + 63) / 64, 256, 0, stream>>>(xb, Wt1, hgW, batch, agg, nullptr);
  k_stats<<<1024, 256, 0, stream>>>(agg, sumsL[3], sumsqL[3], 256);
  k_norm<1, 0><<<(N * 64 + 255) / 256, 256, 0, stream>>>(
      agg, xb, sumsL[3], sumsqL[3], go1, bo1, N * 64, 255);

  // GEMM2: Z1b @ W2 + B2 -> xf (bf16, [N,128]); 128x128 blocks
  k_mgemm<256, 128, 1, 2><<<(N + 127) / 128, 256, 0, stream>>>(xb, Wt2, B2, nullptr, xf, nullptr);
  k_stats<<<1024, 128, 0, stream>>>(xf, sumsL[4], sumsqL[4], 128);
  k_norm<1, 0><<<(N * 32 + 255) / 256, 256, 0, stream>>>(
      xf, xb, sumsL[4], sumsqL[4], go2, bo2, N * 32, 127);

  // GEMM3: Z2b @ W3 + B3 -> split fp32 d_out; 128x128 blocks
  k_mgemm<128, 128, 2, 2><<<(N + 127) / 128, 256, 0, stream>>>(xb, Wt3, B3, nullptr, nullptr, outf);
}

// Round 14
// 529.608 us; speedup vs baseline: 7.5201x; 1.1725x over previous
//
#include <hip/hip_runtime.h>
#include <hip/hip_bf16.h>

namespace {

constexpr int N = 50000;
constexpr int E = 300000;
constexpr int G = 256;
constexpr int H = 256;
constexpr float EPS = 1e-5f;
constexpr int NB = (N + 255) / 256;   // 196 scan blocks
constexpr int POOL_S = 16;
constexpr int GB = 1280;              // gather grid (grid-stride)
constexpr float LOG2E = 1.4426950408889634f;
constexpr float LN2   = 0.6931471805599453f;

typedef unsigned short u16;
typedef __attribute__((ext_vector_type(8))) short bf16x8;
typedef __attribute__((ext_vector_type(4))) float f32x4;

__device__ __forceinline__ float expnabs(float z){
  float r; asm("v_exp_f32 %0, -abs(%1)" : "=v"(r) : "v"(z)); return r;
}
__device__ __forceinline__ float log2f_(float x){
  float r; asm("v_log_f32 %0, %1" : "=v"(r) : "v"(x)); return r;
}
// scaled softplus: input z' = z*log2e; returns log2e*softplus(z)
__device__ __forceinline__ float spw(float zs){
  return fmaxf(zs, 0.f) + log2f_(1.f + expnabs(zs));
}
__device__ __forceinline__ u16 f2b(float f){
  union { float f; unsigned u; } v; v.f = f;
  unsigned r = v.u + 0x7FFF + ((v.u >> 16) & 1);
  return (u16)(r >> 16);
}
__device__ __forceinline__ float b2f(u16 u){
  union { unsigned i; float f; } v; v.i = ((unsigned)u) << 16; return v.f;
}
__device__ __forceinline__ float4 b2f4(ushort4 u){
  return make_float4(b2f(u.x), b2f(u.y), b2f(u.z), b2f(u.w));
}
__device__ __forceinline__ ushort4 f2b4(float4 v){
  ushort4 o; o.x = f2b(v.x); o.y = f2b(v.y); o.z = f2b(v.z); o.w = f2b(v.w);
  return o;
}

// merged prologue: embed (scaled bf16) | edge histogram | weight conversion | eemb*log2e
__global__ void k_pre(const int* __restrict__ nt, const float* __restrict__ nemb,
                      u16* __restrict__ xb, const int* __restrict__ dst,
                      int* __restrict__ cnt,
                      const float* __restrict__ W1, const float* __restrict__ W2,
                      const float* __restrict__ W3, const float* __restrict__ eemb,
                      u16* __restrict__ Wt1, u16* __restrict__ Wt2,
                      u16* __restrict__ Wt3, float* __restrict__ eembF){
  int idx = blockIdx.x * 256 + threadIdx.x;
  if (idx < N * 64){
    int i = idx >> 6, fq = (idx & 63) << 2;
    float4 v = *(const float4*)(nemb + (size_t)nt[i] * H + fq);
    v.x *= LOG2E; v.y *= LOG2E; v.z *= LOG2E; v.w *= LOG2E;
    *(ushort4*)(xb + (size_t)i * H + fq) = f2b4(v);
    return;
  }
  int j = idx - N * 64;
  if (j < E){ atomicAdd(&cnt[dst[j]], 1); return; }
  j -= E;
  if (j < 65536){ int c = j >> 8, k = j & 255; Wt1[j] = f2b(W1[(size_t)k * 256 + c]); return; }
  j -= 65536;
  if (j < 32768){ int c = j >> 8, k = j & 255; Wt2[j] = f2b(W2[(size_t)k * 128 + c]); return; }
  j -= 32768;
  if (j < 16384){ int c = j >> 7, k = j & 127; Wt3[j] = f2b(W3[(size_t)k * 128 + c]); return; }
  j -= 16384;
  if (j < 25600) eembF[j] = eemb[j] * LOG2E;
}

// ---- CSR scan ----
__global__ void k_scan1(const int* __restrict__ cnt, int* __restrict__ bsum){
  __shared__ int s[256];
  int t = threadIdx.x;
  int i = blockIdx.x * 256 + t;
  s[t] = (i < N) ? cnt[i] : 0;
  __syncthreads();
  for (int d = 128; d > 0; d >>= 1){
    if (t < d) s[t] += s[t + d];
    __syncthreads();
  }
  if (t == 0) bsum[blockIdx.x] = s[0];
}

__global__ void k_scan2(const int* __restrict__ bsum, int* __restrict__ bbase){
  __shared__ int s[256];
  int t = threadIdx.x;
  int orig = (t < NB) ? bsum[t] : 0;
  s[t] = orig;
  __syncthreads();
  for (int d = 1; d < 256; d <<= 1){
    int v = (t >= d) ? s[t - d] : 0;
    __syncthreads();
    s[t] += v;
    __syncthreads();
  }
  bbase[t] = s[t] - orig;   // exclusive
}

__global__ void k_scan3(const int* __restrict__ cnt, const int* __restrict__ bbase,
                        int* __restrict__ off, int* __restrict__ cur){
  __shared__ int s[256];
  int t = threadIdx.x;
  int i = blockIdx.x * 256 + t;
  int v = (i < N) ? cnt[i] : 0;
  s[t] = v;
  __syncthreads();
  for (int d = 1; d < 256; d <<= 1){
    int u = (t >= d) ? s[t - d] : 0;
    __syncthreads();
    s[t] += u;
    __syncthreads();
  }
  int excl = bbase[blockIdx.x] + s[t] - v;
  if (i < N){ off[i] = excl; cur[i] = excl; }
  if (i == N - 1) off[N] = excl + v;   // == E
}

// edges_s[p] = (src*512, et*1024): byte offsets into bf16 xb rows / fp32 eembF rows
__global__ void k_fill(const int* __restrict__ src, const int* __restrict__ dst,
                       const int* __restrict__ et, int* __restrict__ cur,
                       int2* __restrict__ edges_s){
  int e = blockIdx.x * 256 + threadIdx.x;
  if (e >= E) return;
  int d = dst[e];
  int p = atomicAdd(&cur[d], 1);
  edges_s[p] = make_int2(src[e] << 9, et[e] << 10);
}

__device__ __forceinline__ void acc_w(float4& acc, const float4 xs, const float4 es){
  acc.x += spw(xs.x + es.x);
  acc.y += spw(xs.y + es.y);
  acc.z += spw(xs.z + es.z);
  acc.w += spw(xs.w + es.w);
}

// gather + fused BN-stats. One wave per node; grid-stride over node-groups of 4.
// agg_true[i] = ln2*(xb_s[i] + sum_e spw(xb_s[src]+eembF_s[et])); stats on pre-round values.
__global__ void k_gather(const u16* __restrict__ xb, u16* __restrict__ agg,
                         const int2* __restrict__ edges_s, const int* __restrict__ off,
                         const float* __restrict__ eembF,
                         float* __restrict__ sums, float* __restrict__ sumsq){
  __shared__ float reds[256][4];
  __shared__ float reds2[256][4];
  int tid = threadIdx.x;
  int w = tid >> 6, lane = tid & 63;
  int fx = lane << 3, fe = lane << 4;
  const char* xB = (const char*)xb;
  const char* eB = (const char*)eembF;
  float4 ls = make_float4(0.f, 0.f, 0.f, 0.f);
  float4 ls2 = make_float4(0.f, 0.f, 0.f, 0.f);
  for (int vb = blockIdx.x; vb < N / 4; vb += GB){
    int i = vb * 4 + w;
    float4 acc = b2f4(*(const ushort4*)(xB + ((size_t)i << 9) + fx));
    int lo = off[i], hi = off[i + 1];
    int j = lo;
    for (; j + 4 <= hi; j += 4){
      int2 s0 = edges_s[j + 0];
      int2 s1 = edges_s[j + 1];
      int2 s2 = edges_s[j + 2];
      int2 s3 = edges_s[j + 3];
      ushort4 x0 = *(const ushort4*)(xB + s0.x + fx);
      ushort4 x1 = *(const ushort4*)(xB + s1.x + fx);
      ushort4 x2 = *(const ushort4*)(xB + s2.x + fx);
      ushort4 x3 = *(const ushort4*)(xB + s3.x + fx);
      float4 e0 = *(const float4*)(eB + s0.y + fe);
      float4 e1 = *(const float4*)(eB + s1.y + fe);
      float4 e2 = *(const float4*)(eB + s2.y + fe);
      float4 e3 = *(const float4*)(eB + s3.y + fe);
      acc_w(acc, b2f4(x0), e0);
      acc_w(acc, b2f4(x1), e1);
      acc_w(acc, b2f4(x2), e2);
      acc_w(acc, b2f4(x3), e3);
    }
    if (j + 2 <= hi){
      int2 s0 = edges_s[j + 0];
      int2 s1 = edges_s[j + 1];
      ushort4 x0 = *(const ushort4*)(xB + s0.x + fx);
      ushort4 x1 = *(const ushort4*)(xB + s1.x + fx);
      float4 e0 = *(const float4*)(eB + s0.y + fe);
      float4 e1 = *(const float4*)(eB + s1.y + fe);
      acc_w(acc, b2f4(x0), e0);
      acc_w(acc, b2f4(x1), e1);
      j += 2;
    }
    if (j < hi){
      int2 s0 = edges_s[j];
      ushort4 x0 = *(const ushort4*)(xB + s0.x + fx);
      float4 e0 = *(const float4*)(eB + s0.y + fe);
      acc_w(acc, b2f4(x0), e0);
    }
    acc.x *= LN2; acc.y *= LN2; acc.z *= LN2; acc.w *= LN2;
    ls.x += acc.x; ls.y += acc.y; ls.z += acc.z; ls.w += acc.w;
    ls2.x += acc.x * acc.x; ls2.y += acc.y * acc.y;
    ls2.z += acc.z * acc.z; ls2.w += acc.w * acc.w;
    *(ushort4*)((char*)agg + ((size_t)i << 9) + fx) = f2b4(acc);
  }
  reds[tid][0] = ls.x;  reds[tid][1] = ls.y;  reds[tid][2] = ls.z;  reds[tid][3] = ls.w;
  reds2[tid][0] = ls2.x; reds2[tid][1] = ls2.y; reds2[tid][2] = ls2.z; reds2[tid][3] = ls2.w;
  __syncthreads();
  // feature f = (lane=f>>2)*4 + (f&3); contributors: waves 0..3 at lane f>>2
  int f = tid;
  float ts = 0.f, ts2 = 0.f;
  #pragma unroll
  for (int w2 = 0; w2 < 4; ++w2){
    int s = w2 * 64 + (f >> 2);
    ts += reds[s][f & 3];
    ts2 += reds2[s][f & 3];
  }
  atomicAdd(&sums[f], ts);
  atomicAdd(&sumsq[f], ts2);
}

// BN-apply, bf16 in -> bf16 out. ACT: softplus. SCALED: output *log2e (for gather input).
template<int ACT, int SCALED>
__global__ void k_norm(const u16* __restrict__ in, u16* __restrict__ outb,
                       const float* __restrict__ sums, const float* __restrict__ sumsq,
                       const float* __restrict__ gamma, const float* __restrict__ beta,
                       int n4, int fmask){
  int idx = blockIdx.x * 256 + threadIdx.x;
  if (idx >= n4) return;
  int base = idx << 2;
  int f = base & fmask;
  float4 s = *(const float4*)(sums + f);
  float4 q = *(const float4*)(sumsq + f);
  float4 g = *(const float4*)(gamma + f);
  float4 bt = *(const float4*)(beta + f);
  float4 v = b2f4(*(const ushort4*)(in + base));
  const float inv = 1.f / N;
  float m, var, a, c;
  m = s.x * inv; var = q.x * inv - m * m; a = g.x * rsqrtf(var + EPS); c = bt.x - m * a; v.x = a * v.x + c;
  m = s.y * inv; var = q.y * inv - m * m; a = g.y * rsqrtf(var + EPS); c = bt.y - m * a; v.y = a * v.y + c;
  m = s.z * inv; var = q.z * inv - m * m; a = g.z * rsqrtf(var + EPS); c = bt.z - m * a; v.z = a * v.z + c;
  m = s.w * inv; var = q.w * inv - m * m; a = g.w * rsqrtf(var + EPS); c = bt.w - m * a; v.w = a * v.w + c;
  if (ACT){
    v.x = spw(v.x * LOG2E); v.y = spw(v.y * LOG2E);
    v.z = spw(v.z * LOG2E); v.w = spw(v.w * LOG2E);
    if (!SCALED){ v.x *= LN2; v.y *= LN2; v.z *= LN2; v.w *= LN2; }
  }
  *(ushort4*)(outb + base) = f2b4(v);
}

// segmented pool over (unscaled) bf16 features: grid (G, POOL_S)
__global__ void k_pool_seg(const u16* __restrict__ xb, const int* __restrict__ batch,
                           float* __restrict__ hg){
  int g = blockIdx.x, sl = blockIdx.y;
  int f = threadIdx.x;
  int lo = 0, hi = N;
  while (lo < hi){ int m = (lo + hi) >> 1; if (batch[m] < g) lo = m + 1; else hi = m; }
  int start = lo;
  lo = 0; hi = N;
  while (lo < hi){ int m = (lo + hi) >> 1; if (batch[m] < g + 1) lo = m + 1; else hi = m; }
  int end = lo;
  int len = end - start;
  int a = start + (int)((long)len * sl / POOL_S);
  int b = start + (int)((long)len * (sl + 1) / POOL_S);
  if (a >= b) return;
  float s = 0.f;
  for (int i = a; i < b; ++i) s += b2f(xb[(size_t)i * H + f]);
  atomicAdd(&hg[g * H + f], s);
}

// hgW[g][c] = sum_k hg[g][k] * W1[256+k][c] + B1[c]
__global__ void k_hgw(const float* __restrict__ hg, const float* __restrict__ W1,
                      const float* __restrict__ B1, float* __restrict__ hgW){
  int g = blockIdx.x, c = threadIdx.x;
  float acc = B1[c];
  for (int k = 0; k < H; ++k)
    acc += hg[g * H + k] * W1[(size_t)(H + k) * H + c];
  hgW[g * H + c] = acc;
}

// MFMA GEMM, 64x64 per wave, + optional fused BN-stats on stored values.
// MODE 0: += hgW[batch[row]] -> bf16; MODE 1: += bias -> bf16; MODE 2: += bias -> split fp32.
template<int K, int NC, int MODE, int WR, int STATS>
__global__ void k_mgemm(const u16* __restrict__ Ab, const u16* __restrict__ Wt,
                        const float* __restrict__ epi, const int* __restrict__ batch,
                        u16* __restrict__ outb, float* __restrict__ outf,
                        float* __restrict__ sums, float* __restrict__ sumsq){
  __shared__ float reds[256][4];
  __shared__ float reds2[256][4];
  constexpr int WC = 4 / WR;
  int tid = threadIdx.x;
  int w = tid >> 6, lane = tid & 63;
  int quad = lane >> 4, l15 = lane & 15;
  int wr = w / WC, wc = w % WC;
  int rowBase = blockIdx.x * (WR * 64) + wr * 64;
  int colBase = wc * 64;
  const u16* arow[4];
  #pragma unroll
  for (int t = 0; t < 4; ++t){
    int am = rowBase + t * 16 + l15;
    if (am >= N) am = N - 1;            // clamp; stores guarded
    arow[t] = Ab + (size_t)am * K + quad * 8;
  }
  const u16* brow[4];
  #pragma unroll
  for (int u = 0; u < 4; ++u)
    brow[u] = Wt + (size_t)(colBase + u * 16 + l15) * K + quad * 8;
  f32x4 acc[4][4] = {};
  for (int k0 = 0; k0 < K; k0 += 32){
    bf16x8 a[4], b[4];
    #pragma unroll
    for (int t = 0; t < 4; ++t) a[t] = *(const bf16x8*)(arow[t] + k0);
    #pragma unroll
    for (int u = 0; u < 4; ++u) b[u] = *(const bf16x8*)(brow[u] + k0);
    #pragma unroll
    for (int t = 0; t < 4; ++t)
      #pragma unroll
      for (int u = 0; u < 4; ++u)
        acc[t][u] = __builtin_amdgcn_mfma_f32_16x16x32_bf16(a[t], b[u], acc[t][u], 0, 0, 0);
  }
  float ls[4] = {0.f, 0.f, 0.f, 0.f};
  float ls2[4] = {0.f, 0.f, 0.f, 0.f};
  #pragma unroll
  for (int t = 0; t < 4; ++t){
    #pragma unroll
    for (int r = 0; r < 4; ++r){
      int row = rowBase + t * 16 + quad * 4 + r;
      if (row >= N) continue;
      int g = (MODE == 0) ? batch[row] : 0;
      #pragma unroll
      for (int u = 0; u < 4; ++u){
        int n = colBase + u * 16 + l15;
        float v = acc[t][u][r];
        if (MODE == 0){
          v += epi[(size_t)g * NC + n];
          outb[(size_t)row * NC + n] = f2b(v);
        } else if (MODE == 1){
          v += epi[n];
          outb[(size_t)row * NC + n] = f2b(v);
        } else {
          v += epi[n];
          if (n < 64) outf[(size_t)row * 64 + n] = v;
          else        outf[(size_t)N * 64 + (size_t)row * 64 + (n - 64)] = v;
        }
        if (STATS){ ls[u] += v; ls2[u] += v * v; }
      }
    }
  }
  if (STATS){
    #pragma unroll
    for (int u = 0; u < 4; ++u){ reds[tid][u] = ls[u]; reds2[tid][u] = ls2[u]; }
    __syncthreads();
    int f = tid;
    if (f < NC){
      int fl = f & 15, fu = (f >> 4) & 3, fw = f >> 6;
      float ts = 0.f, ts2 = 0.f;
      if (WR == 1){
        #pragma unroll
        for (int q = 0; q < 4; ++q){
          int s = fw * 64 + q * 16 + fl;
          ts += reds[s][fu]; ts2 += reds2[s][fu];
        }
      } else {
        #pragma unroll
        for (int r2 = 0; r2 < 2; ++r2)
          #pragma unroll
          for (int q = 0; q < 4; ++q){
            int s = (r2 * 2 + fw) * 64 + q * 16 + fl;
            ts += reds[s][fu]; ts2 += reds2[s][fu];
          }
      }
      atomicAdd(&sums[f], ts);
      atomicAdd(&sumsq[f], ts2);
    }
  }
}

} // namespace

extern "C" void kernel_launch(void* const* d_in, const int* in_sizes, int n_in,
                              void* d_out, int out_size, void* d_ws, size_t ws_size,
                              hipStream_t stream){
  const int* node_type = (const int*)d_in[0];
  const int* edge_type = (const int*)d_in[1];
  const int* src       = (const int*)d_in[2];
  const int* dst       = src + E;
  const int* batch     = (const int*)d_in[3];
  const float* nemb = (const float*)d_in[4];
  const float* eemb = (const float*)d_in[5];
  const float* gs[3] = {(const float*)d_in[6], (const float*)d_in[8], (const float*)d_in[10]};
  const float* bs[3] = {(const float*)d_in[7], (const float*)d_in[9], (const float*)d_in[11]};
  const float* go1 = (const float*)d_in[12]; const float* bo1 = (const float*)d_in[13];
  const float* go2 = (const float*)d_in[14]; const float* bo2 = (const float*)d_in[15];
  const float* W1 = (const float*)d_in[16]; const float* B1 = (const float*)d_in[17];
  const float* W2 = (const float*)d_in[18]; const float* B2 = (const float*)d_in[19];
  const float* W3 = (const float*)d_in[20]; const float* B3 = (const float*)d_in[21];
  float* outf = (float*)d_out;

  // ---- workspace layout: [cnt | hg | statsAll] contiguous => single memset ----
  char* p = (char*)d_ws;
  int*   cnt    = (int*)p;              p += (size_t)N * 4;
  float* hg     = (float*)p;            p += (size_t)G * H * 4;
  float* statsA = (float*)p;            p += 5 * 512 * 4;
  size_t zeroBytes = (size_t)p - (size_t)d_ws;
  float* hgW    = (float*)p;            p += (size_t)G * H * 4;
  int*   off    = (int*)p;              p += (size_t)(N + 1) * 4;
  int*   cur    = (int*)p;              p += (size_t)N * 4;
  int*   bsum   = (int*)p;              p += 256 * 4;
  int*   bbase  = (int*)p;              p += 256 * 4;
  int2*  edges_s= (int2*)p;             p += (size_t)E * 8;
  u16*   xb     = (u16*)p;              p += (size_t)N * H * 2;
  u16*   agg    = (u16*)p;              p += (size_t)N * H * 2;
  u16*   xf     = (u16*)p;              p += (size_t)N * 128 * 2;
  u16*   Wt1    = (u16*)p;              p += 65536 * 2;
  u16*   Wt2    = (u16*)p;              p += 32768 * 2;
  u16*   Wt3    = (u16*)p;              p += 16384 * 2;
  float* eembF  = (float*)p;            p += 25600 * 4;
  float* sumsL[5], *sumsqL[5];
  for (int k = 0; k < 5; ++k){ sumsL[k] = statsA + k * 512; sumsqL[k] = statsA + k * 512 + 256; }

  hipMemsetAsync(d_ws, 0, zeroBytes, stream);   // cnt + hg + all stats

  const int preItems = N * 64 + E + 65536 + 32768 + 16384 + 25600;
  k_pre<<<(preItems + 255) / 256, 256, 0, stream>>>(
      node_type, nemb, xb, dst, cnt, W1, W2, W3, eemb, Wt1, Wt2, Wt3, eembF);
  k_scan1<<<NB, 256, 0, stream>>>(cnt, bsum);
  k_scan2<<<1, 256, 0, stream>>>(bsum, bbase);
  k_scan3<<<NB, 256, 0, stream>>>(cnt, bbase, off, cur);
  k_fill<<<(E + 255) / 256, 256, 0, stream>>>(src, dst, edge_type, cur, edges_s);

  for (int l = 0; l < 3; ++l){
    k_gather<<<GB, 256, 0, stream>>>(xb, agg, edges_s, off, eembF, sumsL[l], sumsqL[l]);
    if (l < 2)
      k_norm<1, 1><<<(N * 64 + 255) / 256, 256, 0, stream>>>(
          agg, xb, sumsL[l], sumsqL[l], gs[l], bs[l], N * 64, 255);
    else  // layer 3: unscaled (feeds pool + GEMM1)
      k_norm<0, 0><<<(N * 64 + 255) / 256, 256, 0, stream>>>(
          agg, xb, sumsL[l], sumsqL[l], gs[l], bs[l], N * 64, 255);
  }

  {
    dim3 pg(G, POOL_S);
    k_pool_seg<<<pg, H, 0, stream>>>(xb, batch, hg);
  }
  k_hgw<<<G, H, 0, stream>>>(hg, W1, B1, hgW);

  // GEMM1 (+stats): xb @ W1top + hgW[batch] -> agg (bf16); 64x256 blocks
  k_mgemm<256, 256, 0, 1, 1><<<(N + 63) / 64, 256, 0, stream>>>(
      xb, Wt1, hgW, batch, agg, nullptr, sumsL[3], sumsqL[3]);
  k_norm<1, 0><<<(N * 64 + 255) / 256, 256, 0, stream>>>(
      agg, xb, sumsL[3], sumsqL[3], go1, bo1, N * 64, 255);

  // GEMM2 (+stats): Z1b @ W2 + B2 -> xf (bf16, [N,128]); 128x128 blocks
  k_mgemm<256, 128, 1, 2, 1><<<(N + 127) / 128, 256, 0, stream>>>(
      xb, Wt2, B2, nullptr, xf, nullptr, sumsL[4], sumsqL[4]);
  k_norm<1, 0><<<(N * 32 + 255) / 256, 256, 0, stream>>>(
      xf, xb, sumsL[4], sumsqL[4], go2, bo2, N * 32, 127);

  // GEMM3: Z2b @ W3 + B3 -> split fp32 d_out; 128x128 blocks
  k_mgemm<128, 128, 2, 2, 0><<<(N + 127) / 128, 256, 0, stream>>>(
      xb, Wt3, B3, nullptr, nullptr, outf, nullptr, nullptr);
}